// Round 1
// baseline (1386.633 us; speedup 1.0000x reference)
//
#include <hip/hip_runtime.h>
#include <math.h>

#define NN 50000
#define NE 800000
#define DIN 128
#define DH 64
#define NLAYERS 8
#define SCAN_B 256
#define NB ((NN + SCAN_B - 1) / SCAN_B)   // 196

// ---------------- setup kernels ----------------

__global__ void k_count(const int* __restrict__ ei, int* __restrict__ cnt) {
    int stride = gridDim.x * blockDim.x;
    for (int e = blockIdx.x * blockDim.x + threadIdx.x; e < NE; e += stride) {
        int d = ei[NE + e];
        atomicAdd(&cnt[d], 1);
    }
}

__global__ void k_dinv(const int* __restrict__ cnt, float* __restrict__ dinv) {
    int i = blockIdx.x * blockDim.x + threadIdx.x;
    if (i < NN) dinv[i] = rsqrtf((float)(cnt[i] + 1));   // +1 self-loop
}

__global__ void k_blocksum(const int* __restrict__ cnt, int* __restrict__ bsum) {
    __shared__ int s[SCAN_B];
    int i = blockIdx.x * SCAN_B + threadIdx.x;
    s[threadIdx.x] = (i < NN) ? cnt[i] : 0;
    __syncthreads();
    for (int off = SCAN_B / 2; off > 0; off >>= 1) {
        if (threadIdx.x < off) s[threadIdx.x] += s[threadIdx.x + off];
        __syncthreads();
    }
    if (threadIdx.x == 0) bsum[blockIdx.x] = s[0];
}

__global__ void k_scan_bsum(const int* __restrict__ bsum, int* __restrict__ boff) {
    __shared__ int s[SCAN_B];
    int t = threadIdx.x;
    s[t] = (t < NB) ? bsum[t] : 0;
    __syncthreads();
    for (int off = 1; off < SCAN_B; off <<= 1) {
        int v = (t >= off) ? s[t - off] : 0;
        __syncthreads();
        s[t] += v;
        __syncthreads();
    }
    if (t < NB) boff[t] = (t == 0) ? 0 : s[t - 1];
}

__global__ void k_scan_final(const int* __restrict__ cnt, const int* __restrict__ boff,
                             int* __restrict__ offs, int* __restrict__ cursor) {
    __shared__ int s[SCAN_B];
    int t = threadIdx.x;
    int i = blockIdx.x * SCAN_B + t;
    int v = (i < NN) ? cnt[i] : 0;
    s[t] = v;
    __syncthreads();
    for (int off = 1; off < SCAN_B; off <<= 1) {
        int u = (t >= off) ? s[t - off] : 0;
        __syncthreads();
        s[t] += u;
        __syncthreads();
    }
    if (i < NN) {
        int excl = boff[blockIdx.x] + s[t] - v;
        offs[i] = excl;
        cursor[i] = excl;
        if (i == NN - 1) offs[NN] = excl + v;
    }
}

__global__ void k_fill(const int* __restrict__ ei, const float* __restrict__ dinv,
                       int* __restrict__ cursor, int* __restrict__ csr_src,
                       float* __restrict__ csr_w) {
    int stride = gridDim.x * blockDim.x;
    for (int e = blockIdx.x * blockDim.x + threadIdx.x; e < NE; e += stride) {
        int s = ei[e];
        int d = ei[NE + e];
        int p = atomicAdd(&cursor[d], 1);
        csr_src[p] = s;
        csr_w[p] = dinv[s];
    }
}

// M[l] = (1-beta_l)*I + beta_l*Ws[l]
__global__ void k_makeM(const float* __restrict__ Ws, float* __restrict__ M) {
    int l = blockIdx.x;
    float beta = logf(0.5f / (float)(l + 1) + 1.0f);
    for (int idx = threadIdx.x; idx < DH * DH; idx += blockDim.x) {
        int k = idx >> 6, j = idx & 63;
        float v = beta * Ws[l * DH * DH + idx];
        if (k == j) v += 1.0f - beta;
        M[l * DH * DH + idx] = v;
    }
}

// ---------------- compute kernels ----------------

// h = relu(x @ W0 + b0); also write h0
__global__ __launch_bounds__(256) void k_layer0(const float* __restrict__ x,
                                                const float* __restrict__ W0,
                                                const float* __restrict__ b0,
                                                float* __restrict__ h,
                                                float* __restrict__ h0) {
    __shared__ float w[DIN * DH];   // 32 KB
    for (int idx = threadIdx.x; idx < DIN * DH; idx += 256) w[idx] = W0[idx];
    __syncthreads();
    int lane = threadIdx.x & 63;
    int wave = threadIdx.x >> 6;
    int gwave = blockIdx.x * 4 + wave;
    int nwaves = gridDim.x * 4;
    float bb = b0[lane];
    for (int i = gwave; i < NN; i += nwaves) {
        float xlo = x[(size_t)i * DIN + lane];
        float xhi = x[(size_t)i * DIN + 64 + lane];
        float acc = 0.f;
#pragma unroll
        for (int k = 0; k < 64; k++) {
            float xa = __shfl(xlo, k);
            float xb = __shfl(xhi, k);
            acc += xa * w[k * DH + lane];
            acc += xb * w[(k + 64) * DH + lane];
        }
        acc = fmaxf(acc + bb, 0.f);
        h[(size_t)i * DH + lane] = acc;
        h0[(size_t)i * DH + lane] = acc;
    }
}

// one GCNII layer: ah = D^-1/2 A D^-1/2 h (incl self-loop); xx = .9 ah + .1 h0;
// h_out = relu(xx @ M_l)
__global__ __launch_bounds__(256) void k_layer(const float* __restrict__ hin,
                                               const float* __restrict__ h0,
                                               const float* __restrict__ Mall, int layer,
                                               const int* __restrict__ offs,
                                               const int* __restrict__ csr_src,
                                               const float* __restrict__ csr_w,
                                               const float* __restrict__ dinv,
                                               float* __restrict__ hout) {
    __shared__ float m[DH * DH];   // 16 KB
    const float* M = Mall + (size_t)layer * DH * DH;
    for (int idx = threadIdx.x; idx < DH * DH; idx += 256) m[idx] = M[idx];
    __syncthreads();
    int lane = threadIdx.x & 63;
    int wave = threadIdx.x >> 6;
    int gwave = blockIdx.x * 4 + wave;
    int nwaves = gridDim.x * 4;
    for (int i = gwave; i < NN; i += nwaves) {
        int b = offs[i], e = offs[i + 1];
        float acc = 0.f;
        for (int p = b; p < e; p++) {
            int s = csr_src[p];
            float wv = csr_w[p];
            acc += wv * hin[(size_t)s * DH + lane];
        }
        float di = dinv[i];
        acc = di * (acc + di * hin[(size_t)i * DH + lane]);
        float xx = 0.9f * acc + 0.1f * h0[(size_t)i * DH + lane];
        float y = 0.f;
#pragma unroll
        for (int k = 0; k < 64; k++) {
            float xk = __shfl(xx, k);
            y += xk * m[k * DH + lane];
        }
        hout[(size_t)i * DH + lane] = fmaxf(y, 0.f);
    }
}

// out = h @ W_out + b_out
__global__ __launch_bounds__(256) void k_out(const float* __restrict__ hin,
                                             const float* __restrict__ Wout,
                                             const float* __restrict__ bout,
                                             float* __restrict__ out) {
    __shared__ float m[DH * DH];
    for (int idx = threadIdx.x; idx < DH * DH; idx += 256) m[idx] = Wout[idx];
    __syncthreads();
    int lane = threadIdx.x & 63;
    int wave = threadIdx.x >> 6;
    int gwave = blockIdx.x * 4 + wave;
    int nwaves = gridDim.x * 4;
    float bb = bout[lane];
    for (int i = gwave; i < NN; i += nwaves) {
        float xx = hin[(size_t)i * DH + lane];
        float y = 0.f;
#pragma unroll
        for (int k = 0; k < 64; k++) {
            float xk = __shfl(xx, k);
            y += xk * m[k * DH + lane];
        }
        out[(size_t)i * DH + lane] = y + bb;
    }
}

// ---------------- launch ----------------

static inline size_t al256(size_t x) { return (x + 255) & ~(size_t)255; }

extern "C" void kernel_launch(void* const* d_in, const int* in_sizes, int n_in,
                              void* d_out, int out_size, void* d_ws, size_t ws_size,
                              hipStream_t stream) {
    const float* x    = (const float*)d_in[0];
    const int*   ei   = (const int*)d_in[1];
    const float* W0   = (const float*)d_in[2];
    const float* b0   = (const float*)d_in[3];
    const float* Ws   = (const float*)d_in[4];
    const float* Wout = (const float*)d_in[5];
    const float* bout = (const float*)d_in[6];
    float* out = (float*)d_out;

    char* w = (char*)d_ws;
    size_t off = 0;
    int* cnt     = (int*)(w + off); off = al256(off + (size_t)NN * 4);
    int* offs    = (int*)(w + off); off = al256(off + ((size_t)NN + 1) * 4);
    int* cursor  = (int*)(w + off); off = al256(off + (size_t)NN * 4);
    int* bsum    = (int*)(w + off); off = al256(off + (size_t)SCAN_B * 4);
    int* boff    = (int*)(w + off); off = al256(off + (size_t)SCAN_B * 4);
    int* csr_src = (int*)(w + off); off = al256(off + (size_t)NE * 4);
    float* csr_w = (float*)(w + off); off = al256(off + (size_t)NE * 4);
    float* dinv  = (float*)(w + off); off = al256(off + (size_t)NN * 4);
    float* M     = (float*)(w + off); off = al256(off + (size_t)NLAYERS * DH * DH * 4);
    float* hA    = (float*)(w + off); off = al256(off + (size_t)NN * DH * 4);
    float* hB    = (float*)(w + off); off = al256(off + (size_t)NN * DH * 4);
    float* h0    = (float*)(w + off); off = al256(off + (size_t)NN * DH * 4);

    hipMemsetAsync(cnt, 0, (size_t)NN * 4, stream);

    k_count<<<1024, 256, 0, stream>>>(ei, cnt);
    k_dinv<<<(NN + 255) / 256, 256, 0, stream>>>(cnt, dinv);
    k_blocksum<<<NB, SCAN_B, 0, stream>>>(cnt, bsum);
    k_scan_bsum<<<1, SCAN_B, 0, stream>>>(bsum, boff);
    k_scan_final<<<NB, SCAN_B, 0, stream>>>(cnt, boff, offs, cursor);
    k_fill<<<1024, 256, 0, stream>>>(ei, dinv, cursor, csr_src, csr_w);
    k_makeM<<<NLAYERS, 256, 0, stream>>>(Ws, M);

    k_layer0<<<2048, 256, 0, stream>>>(x, W0, b0, hA, h0);

    const float* cur = hA;
    float* nxt = hB;
    for (int l = 0; l < NLAYERS; l++) {
        k_layer<<<2048, 256, 0, stream>>>(cur, h0, M, l, offs, csr_src, csr_w, dinv, nxt);
        const float* t = nxt;
        nxt = (float*)cur;
        cur = t;
    }
    k_out<<<2048, 256, 0, stream>>>(cur, Wout, bout, out);
}

// Round 2
// 1017.243 us; speedup vs baseline: 1.3631x; 1.3631x over previous
//
#include <hip/hip_runtime.h>
#include <math.h>

#define NN 50000
#define NE 800000
#define DIN 128
#define DH 64
#define NLAYERS 8
#define SCAN_B 256
#define NB ((NN + SCAN_B - 1) / SCAN_B)   // 196

// ---------------- setup kernels ----------------

__global__ void k_count(const int* __restrict__ ei, int* __restrict__ cnt) {
    int stride = gridDim.x * blockDim.x;
    for (int e = blockIdx.x * blockDim.x + threadIdx.x; e < NE; e += stride) {
        int d = ei[NE + e];
        atomicAdd(&cnt[d], 1);
    }
}

__global__ void k_dinv(const int* __restrict__ cnt, float* __restrict__ dinv) {
    int i = blockIdx.x * blockDim.x + threadIdx.x;
    if (i < NN) dinv[i] = rsqrtf((float)(cnt[i] + 1));   // +1 self-loop
}

__global__ void k_blocksum(const int* __restrict__ cnt, int* __restrict__ bsum) {
    __shared__ int s[SCAN_B];
    int i = blockIdx.x * SCAN_B + threadIdx.x;
    s[threadIdx.x] = (i < NN) ? cnt[i] : 0;
    __syncthreads();
    for (int off = SCAN_B / 2; off > 0; off >>= 1) {
        if (threadIdx.x < off) s[threadIdx.x] += s[threadIdx.x + off];
        __syncthreads();
    }
    if (threadIdx.x == 0) bsum[blockIdx.x] = s[0];
}

__global__ void k_scan_bsum(const int* __restrict__ bsum, int* __restrict__ boff) {
    __shared__ int s[SCAN_B];
    int t = threadIdx.x;
    s[t] = (t < NB) ? bsum[t] : 0;
    __syncthreads();
    for (int off = 1; off < SCAN_B; off <<= 1) {
        int v = (t >= off) ? s[t - off] : 0;
        __syncthreads();
        s[t] += v;
        __syncthreads();
    }
    if (t < NB) boff[t] = (t == 0) ? 0 : s[t - 1];
}

__global__ void k_scan_final(const int* __restrict__ cnt, const int* __restrict__ boff,
                             int* __restrict__ offs, int* __restrict__ cursor) {
    __shared__ int s[SCAN_B];
    int t = threadIdx.x;
    int i = blockIdx.x * SCAN_B + t;
    int v = (i < NN) ? cnt[i] : 0;
    s[t] = v;
    __syncthreads();
    for (int off = 1; off < SCAN_B; off <<= 1) {
        int u = (t >= off) ? s[t - off] : 0;
        __syncthreads();
        s[t] += u;
        __syncthreads();
    }
    if (i < NN) {
        int excl = boff[blockIdx.x] + s[t] - v;
        offs[i] = excl;
        cursor[i] = excl;
        if (i == NN - 1) offs[NN] = excl + v;
    }
}

// packed CSR entry: .x = src node, .y = dinv[src] bits
__global__ void k_fill(const int* __restrict__ ei, const float* __restrict__ dinv,
                       int* __restrict__ cursor, int2* __restrict__ csr) {
    int stride = gridDim.x * blockDim.x;
    for (int e = blockIdx.x * blockDim.x + threadIdx.x; e < NE; e += stride) {
        int s = ei[e];
        int d = ei[NE + e];
        int p = atomicAdd(&cursor[d], 1);
        int2 c;
        c.x = s;
        c.y = __float_as_int(dinv[s]);
        csr[p] = c;
    }
}

// M[l] = (1-beta_l)*I + beta_l*Ws[l]
__global__ void k_makeM(const float* __restrict__ Ws, float* __restrict__ M) {
    int l = blockIdx.x;
    float beta = logf(0.5f / (float)(l + 1) + 1.0f);
    for (int idx = threadIdx.x; idx < DH * DH; idx += blockDim.x) {
        int k = idx >> 6, j = idx & 63;
        float v = beta * Ws[l * DH * DH + idx];
        if (k == j) v += 1.0f - beta;
        M[l * DH * DH + idx] = v;
    }
}

// ---------------- compute kernels ----------------

// h = relu(x @ W0 + b0); also write h0
__global__ __launch_bounds__(256) void k_layer0(const float* __restrict__ x,
                                                const float* __restrict__ W0,
                                                const float* __restrict__ b0,
                                                float* __restrict__ h,
                                                float* __restrict__ h0) {
    __shared__ float w[DIN * DH];   // 32 KB
    for (int idx = threadIdx.x; idx < DIN * DH; idx += 256) w[idx] = W0[idx];
    __syncthreads();
    int lane = threadIdx.x & 63;
    int wave = threadIdx.x >> 6;
    int gwave = blockIdx.x * 4 + wave;
    int nwaves = gridDim.x * 4;
    float bb = b0[lane];
    for (int i = gwave; i < NN; i += nwaves) {
        float xlo = x[(size_t)i * DIN + lane];
        float xhi = x[(size_t)i * DIN + 64 + lane];
        float acc = 0.f;
#pragma unroll
        for (int k = 0; k < 64; k++) {
            float xa = __shfl(xlo, k);
            float xb = __shfl(xhi, k);
            acc += xa * w[k * DH + lane];
            acc += xb * w[(k + 64) * DH + lane];
        }
        acc = fmaxf(acc + bb, 0.f);
        h[(size_t)i * DH + lane] = acc;
        h0[(size_t)i * DH + lane] = acc;
    }
}

// one GCNII layer: ah = D^-1/2 A D^-1/2 h (incl self-loop); xx = .9 ah + .1 h0;
// h_out = relu(xx @ M_l)
// Edge loop is 8-way unrolled: 8 independent gathers in flight per wave
// (latency-bound gather needs MLP, see R1 counters: VALUBusy 13%, BW 707 GB/s).
__global__ __launch_bounds__(256) void k_layer(const float* __restrict__ hin,
                                               const float* __restrict__ h0,
                                               const float* __restrict__ Mall, int layer,
                                               const int* __restrict__ offs,
                                               const int2* __restrict__ csr,
                                               const float* __restrict__ dinv,
                                               float* __restrict__ hout) {
    __shared__ float m[DH * DH];   // 16 KB
    const float* M = Mall + (size_t)layer * DH * DH;
    for (int idx = threadIdx.x; idx < DH * DH; idx += 256) m[idx] = M[idx];
    __syncthreads();
    int lane = threadIdx.x & 63;
    int wave = threadIdx.x >> 6;
    int gwave = blockIdx.x * 4 + wave;
    int nwaves = gridDim.x * 4;
    for (int i = gwave; i < NN; i += nwaves) {
        int b = offs[i], e = offs[i + 1];
        // independent loads issued up-front
        float hself = hin[(size_t)i * DH + lane];
        float h0v = h0[(size_t)i * DH + lane];
        float di = dinv[i];
        float a0 = 0.f, a1 = 0.f, a2 = 0.f, a3 = 0.f;
        float a4 = 0.f, a5 = 0.f, a6 = 0.f, a7 = 0.f;
        int p = b;
        for (; p + 8 <= e; p += 8) {
            int2 c0 = csr[p + 0], c1 = csr[p + 1], c2 = csr[p + 2], c3 = csr[p + 3];
            int2 c4 = csr[p + 4], c5 = csr[p + 5], c6 = csr[p + 6], c7 = csr[p + 7];
            float g0 = hin[(size_t)c0.x * DH + lane];
            float g1 = hin[(size_t)c1.x * DH + lane];
            float g2 = hin[(size_t)c2.x * DH + lane];
            float g3 = hin[(size_t)c3.x * DH + lane];
            float g4 = hin[(size_t)c4.x * DH + lane];
            float g5 = hin[(size_t)c5.x * DH + lane];
            float g6 = hin[(size_t)c6.x * DH + lane];
            float g7 = hin[(size_t)c7.x * DH + lane];
            a0 = fmaf(__int_as_float(c0.y), g0, a0);
            a1 = fmaf(__int_as_float(c1.y), g1, a1);
            a2 = fmaf(__int_as_float(c2.y), g2, a2);
            a3 = fmaf(__int_as_float(c3.y), g3, a3);
            a4 = fmaf(__int_as_float(c4.y), g4, a4);
            a5 = fmaf(__int_as_float(c5.y), g5, a5);
            a6 = fmaf(__int_as_float(c6.y), g6, a6);
            a7 = fmaf(__int_as_float(c7.y), g7, a7);
        }
        if (p + 4 <= e) {
            int2 c0 = csr[p + 0], c1 = csr[p + 1], c2 = csr[p + 2], c3 = csr[p + 3];
            float g0 = hin[(size_t)c0.x * DH + lane];
            float g1 = hin[(size_t)c1.x * DH + lane];
            float g2 = hin[(size_t)c2.x * DH + lane];
            float g3 = hin[(size_t)c3.x * DH + lane];
            a0 = fmaf(__int_as_float(c0.y), g0, a0);
            a1 = fmaf(__int_as_float(c1.y), g1, a1);
            a2 = fmaf(__int_as_float(c2.y), g2, a2);
            a3 = fmaf(__int_as_float(c3.y), g3, a3);
            p += 4;
        }
        for (; p < e; ++p) {
            int2 c = csr[p];
            a0 = fmaf(__int_as_float(c.y), hin[(size_t)c.x * DH + lane], a0);
        }
        float acc = ((a0 + a1) + (a2 + a3)) + ((a4 + a5) + (a6 + a7));
        acc = di * (acc + di * hself);
        float xx = 0.9f * acc + 0.1f * h0v;
        float y = 0.f;
#pragma unroll
        for (int k = 0; k < 64; k++) {
            float xk = __shfl(xx, k);
            y += xk * m[k * DH + lane];
        }
        hout[(size_t)i * DH + lane] = fmaxf(y, 0.f);
    }
}

// out = h @ W_out + b_out
__global__ __launch_bounds__(256) void k_out(const float* __restrict__ hin,
                                             const float* __restrict__ Wout,
                                             const float* __restrict__ bout,
                                             float* __restrict__ out) {
    __shared__ float m[DH * DH];
    for (int idx = threadIdx.x; idx < DH * DH; idx += 256) m[idx] = Wout[idx];
    __syncthreads();
    int lane = threadIdx.x & 63;
    int wave = threadIdx.x >> 6;
    int gwave = blockIdx.x * 4 + wave;
    int nwaves = gridDim.x * 4;
    float bb = bout[lane];
    for (int i = gwave; i < NN; i += nwaves) {
        float xx = hin[(size_t)i * DH + lane];
        float y = 0.f;
#pragma unroll
        for (int k = 0; k < 64; k++) {
            float xk = __shfl(xx, k);
            y += xk * m[k * DH + lane];
        }
        out[(size_t)i * DH + lane] = y + bb;
    }
}

// ---------------- launch ----------------

static inline size_t al256(size_t x) { return (x + 255) & ~(size_t)255; }

extern "C" void kernel_launch(void* const* d_in, const int* in_sizes, int n_in,
                              void* d_out, int out_size, void* d_ws, size_t ws_size,
                              hipStream_t stream) {
    const float* x    = (const float*)d_in[0];
    const int*   ei   = (const int*)d_in[1];
    const float* W0   = (const float*)d_in[2];
    const float* b0   = (const float*)d_in[3];
    const float* Ws   = (const float*)d_in[4];
    const float* Wout = (const float*)d_in[5];
    const float* bout = (const float*)d_in[6];
    float* out = (float*)d_out;

    char* w = (char*)d_ws;
    size_t off = 0;
    int* cnt     = (int*)(w + off); off = al256(off + (size_t)NN * 4);
    int* offs    = (int*)(w + off); off = al256(off + ((size_t)NN + 1) * 4);
    int* cursor  = (int*)(w + off); off = al256(off + (size_t)NN * 4);
    int* bsum    = (int*)(w + off); off = al256(off + (size_t)SCAN_B * 4);
    int* boff    = (int*)(w + off); off = al256(off + (size_t)SCAN_B * 4);
    int2* csr    = (int2*)(w + off); off = al256(off + (size_t)NE * 8);
    float* dinv  = (float*)(w + off); off = al256(off + (size_t)NN * 4);
    float* M     = (float*)(w + off); off = al256(off + (size_t)NLAYERS * DH * DH * 4);
    float* hA    = (float*)(w + off); off = al256(off + (size_t)NN * DH * 4);
    float* hB    = (float*)(w + off); off = al256(off + (size_t)NN * DH * 4);
    float* h0    = (float*)(w + off); off = al256(off + (size_t)NN * DH * 4);

    hipMemsetAsync(cnt, 0, (size_t)NN * 4, stream);

    k_count<<<1024, 256, 0, stream>>>(ei, cnt);
    k_dinv<<<(NN + 255) / 256, 256, 0, stream>>>(cnt, dinv);
    k_blocksum<<<NB, SCAN_B, 0, stream>>>(cnt, bsum);
    k_scan_bsum<<<1, SCAN_B, 0, stream>>>(bsum, boff);
    k_scan_final<<<NB, SCAN_B, 0, stream>>>(cnt, boff, offs, cursor);
    k_fill<<<1024, 256, 0, stream>>>(ei, dinv, cursor, csr);
    k_makeM<<<NLAYERS, 256, 0, stream>>>(Ws, M);

    k_layer0<<<2048, 256, 0, stream>>>(x, W0, b0, hA, h0);

    const float* cur = hA;
    float* nxt = hB;
    for (int l = 0; l < NLAYERS; l++) {
        k_layer<<<2048, 256, 0, stream>>>(cur, h0, M, l, offs, csr, dinv, nxt);
        const float* t = nxt;
        nxt = (float*)cur;
        cur = t;
    }
    k_out<<<2048, 256, 0, stream>>>(cur, Wout, bout, out);
}

// Round 3
// 747.481 us; speedup vs baseline: 1.8551x; 1.3609x over previous
//
#include <hip/hip_runtime.h>
#include <hip/hip_fp16.h>
#include <math.h>

#define NN 50000
#define NE 800000
#define DIN 128
#define DH 64
#define NP 32            // __half2 pairs per row
#define NLAYERS 8
#define SCAN_B 256
#define NB ((NN + SCAN_B - 1) / SCAN_B)   // 196

// ---------------- setup kernels ----------------

__global__ void k_count(const int* __restrict__ ei, int* __restrict__ cnt) {
    int stride = gridDim.x * blockDim.x;
    for (int e = blockIdx.x * blockDim.x + threadIdx.x; e < NE; e += stride) {
        int d = ei[NE + e];
        atomicAdd(&cnt[d], 1);
    }
}

__global__ void k_dinv(const int* __restrict__ cnt, float* __restrict__ dinv) {
    int i = blockIdx.x * blockDim.x + threadIdx.x;
    if (i < NN) dinv[i] = rsqrtf((float)(cnt[i] + 1));   // +1 self-loop
}

__global__ void k_blocksum(const int* __restrict__ cnt, int* __restrict__ bsum) {
    __shared__ int s[SCAN_B];
    int i = blockIdx.x * SCAN_B + threadIdx.x;
    s[threadIdx.x] = (i < NN) ? cnt[i] : 0;
    __syncthreads();
    for (int off = SCAN_B / 2; off > 0; off >>= 1) {
        if (threadIdx.x < off) s[threadIdx.x] += s[threadIdx.x + off];
        __syncthreads();
    }
    if (threadIdx.x == 0) bsum[blockIdx.x] = s[0];
}

__global__ void k_scan_bsum(const int* __restrict__ bsum, int* __restrict__ boff) {
    __shared__ int s[SCAN_B];
    int t = threadIdx.x;
    s[t] = (t < NB) ? bsum[t] : 0;
    __syncthreads();
    for (int off = 1; off < SCAN_B; off <<= 1) {
        int v = (t >= off) ? s[t - off] : 0;
        __syncthreads();
        s[t] += v;
        __syncthreads();
    }
    if (t < NB) boff[t] = (t == 0) ? 0 : s[t - 1];
}

__global__ void k_scan_final(const int* __restrict__ cnt, const int* __restrict__ boff,
                             int* __restrict__ offs, int* __restrict__ cursor) {
    __shared__ int s[SCAN_B];
    int t = threadIdx.x;
    int i = blockIdx.x * SCAN_B + t;
    int v = (i < NN) ? cnt[i] : 0;
    s[t] = v;
    __syncthreads();
    for (int off = 1; off < SCAN_B; off <<= 1) {
        int u = (t >= off) ? s[t - off] : 0;
        __syncthreads();
        s[t] += u;
        __syncthreads();
    }
    if (i < NN) {
        int excl = boff[blockIdx.x] + s[t] - v;
        offs[i] = excl;
        cursor[i] = excl;
        if (i == NN - 1) offs[NN] = excl + v;
    }
}

// packed CSR entry: .x = src node, .y = dinv[src] bits
__global__ void k_fill(const int* __restrict__ ei, const float* __restrict__ dinv,
                       int* __restrict__ cursor, int2* __restrict__ csr) {
    int stride = gridDim.x * blockDim.x;
    for (int e = blockIdx.x * blockDim.x + threadIdx.x; e < NE; e += stride) {
        int s = ei[e];
        int d = ei[NE + e];
        int p = atomicAdd(&cursor[d], 1);
        int2 c;
        c.x = s;
        c.y = __float_as_int(dinv[s]);
        csr[p] = c;
    }
}

// M[l] = (1-beta_l)*I + beta_l*Ws[l]
__global__ void k_makeM(const float* __restrict__ Ws, float* __restrict__ M) {
    int l = blockIdx.x;
    float beta = logf(0.5f / (float)(l + 1) + 1.0f);
    for (int idx = threadIdx.x; idx < DH * DH; idx += blockDim.x) {
        int k = idx >> 6, j = idx & 63;
        float v = beta * Ws[l * DH * DH + idx];
        if (k == j) v += 1.0f - beta;
        M[l * DH * DH + idx] = v;
    }
}

// ---------------- compute kernels ----------------

// h = relu(x @ W0 + b0); write h (fp16 pairs) and h0 (fp16 pairs)
__global__ __launch_bounds__(256) void k_layer0(const float* __restrict__ x,
                                                const float* __restrict__ W0,
                                                const float* __restrict__ b0,
                                                __half2* __restrict__ h,
                                                __half2* __restrict__ h0) {
    __shared__ float w[DIN * DH];   // 32 KB
    for (int idx = threadIdx.x; idx < DIN * DH; idx += 256) w[idx] = W0[idx];
    __syncthreads();
    int lane = threadIdx.x & 63;
    int wave = threadIdx.x >> 6;
    int gwave = blockIdx.x * 4 + wave;
    int nwaves = gridDim.x * 4;
    float bb = b0[lane];
    for (int i = gwave; i < NN; i += nwaves) {
        float xlo = x[(size_t)i * DIN + lane];
        float xhi = x[(size_t)i * DIN + 64 + lane];
        float acc = 0.f;
#pragma unroll
        for (int k = 0; k < 64; k++) {
            float xa = __shfl(xlo, k);
            float xb = __shfl(xhi, k);
            acc += xa * w[k * DH + lane];
            acc += xb * w[(k + 64) * DH + lane];
        }
        acc = fmaxf(acc + bb, 0.f);
        float yo = __shfl(acc, lane | 1);   // odd partner's value
        if (!(lane & 1)) {
            __half2 hp = __floats2half2_rn(acc, yo);   // low = even feat
            h[(i << 5) + (lane >> 1)] = hp;
            h0[(i << 5) + (lane >> 1)] = hp;
        }
    }
}

// one GCNII layer. hin fp16 pair layout: hin[i*32+p] = (feat 2p, feat 2p+1).
// Gather: lanes 0-31 process even edges, 32-63 odd edges; each lane loads one
// __half2 (4B) -> one instruction fetches TWO 128B rows (2x rows in flight,
// half the line traffic vs fp32).
__global__ __launch_bounds__(256) void k_layer(const __half2* __restrict__ hin,
                                               const __half2* __restrict__ h0,
                                               const float* __restrict__ Mall, int layer,
                                               const int* __restrict__ offs,
                                               const int2* __restrict__ csr,
                                               const float* __restrict__ dinv,
                                               __half2* __restrict__ hout) {
    __shared__ float m[DH * DH];   // 16 KB
    const float* M = Mall + (size_t)layer * DH * DH;
    for (int idx = threadIdx.x; idx < DH * DH; idx += 256) m[idx] = M[idx];
    __syncthreads();
    int lane = threadIdx.x & 63;
    int q = lane >> 5;      // edge parity this lane handles
    int pp = lane & 31;     // pair index this lane handles
    int wave = threadIdx.x >> 6;
    int gwave = blockIdx.x * 4 + wave;
    int nwaves = gridDim.x * 4;
    for (int i = gwave; i < NN; i += nwaves) {
        int b = offs[i], e = offs[i + 1];
        float ax0 = 0.f, ay0 = 0.f, ax1 = 0.f, ay1 = 0.f;
        float ax2 = 0.f, ay2 = 0.f, ax3 = 0.f, ay3 = 0.f;
        int p = b;
        for (; p + 16 <= e; p += 16) {   // 16 edges: 8 half2 gathers in flight
            int2 c0 = csr[p + 0 + q],  c1 = csr[p + 2 + q];
            int2 c2 = csr[p + 4 + q],  c3 = csr[p + 6 + q];
            int2 c4 = csr[p + 8 + q],  c5 = csr[p + 10 + q];
            int2 c6 = csr[p + 12 + q], c7 = csr[p + 14 + q];
            __half2 g0 = hin[(c0.x << 5) + pp];
            __half2 g1 = hin[(c1.x << 5) + pp];
            __half2 g2 = hin[(c2.x << 5) + pp];
            __half2 g3 = hin[(c3.x << 5) + pp];
            __half2 g4 = hin[(c4.x << 5) + pp];
            __half2 g5 = hin[(c5.x << 5) + pp];
            __half2 g6 = hin[(c6.x << 5) + pp];
            __half2 g7 = hin[(c7.x << 5) + pp];
            float2 f0 = __half22float2(g0), f1 = __half22float2(g1);
            float2 f2 = __half22float2(g2), f3 = __half22float2(g3);
            float2 f4 = __half22float2(g4), f5 = __half22float2(g5);
            float2 f6 = __half22float2(g6), f7 = __half22float2(g7);
            float w0 = __int_as_float(c0.y), w1 = __int_as_float(c1.y);
            float w2 = __int_as_float(c2.y), w3 = __int_as_float(c3.y);
            float w4 = __int_as_float(c4.y), w5 = __int_as_float(c5.y);
            float w6 = __int_as_float(c6.y), w7 = __int_as_float(c7.y);
            ax0 = fmaf(w0, f0.x, ax0); ay0 = fmaf(w0, f0.y, ay0);
            ax1 = fmaf(w1, f1.x, ax1); ay1 = fmaf(w1, f1.y, ay1);
            ax2 = fmaf(w2, f2.x, ax2); ay2 = fmaf(w2, f2.y, ay2);
            ax3 = fmaf(w3, f3.x, ax3); ay3 = fmaf(w3, f3.y, ay3);
            ax0 = fmaf(w4, f4.x, ax0); ay0 = fmaf(w4, f4.y, ay0);
            ax1 = fmaf(w5, f5.x, ax1); ay1 = fmaf(w5, f5.y, ay1);
            ax2 = fmaf(w6, f6.x, ax2); ay2 = fmaf(w6, f6.y, ay2);
            ax3 = fmaf(w7, f7.x, ax3); ay3 = fmaf(w7, f7.y, ay3);
        }
        if (p + 8 <= e) {   // 8 edges unmasked
            int2 c0 = csr[p + 0 + q], c1 = csr[p + 2 + q];
            int2 c2 = csr[p + 4 + q], c3 = csr[p + 6 + q];
            __half2 g0 = hin[(c0.x << 5) + pp];
            __half2 g1 = hin[(c1.x << 5) + pp];
            __half2 g2 = hin[(c2.x << 5) + pp];
            __half2 g3 = hin[(c3.x << 5) + pp];
            float2 f0 = __half22float2(g0), f1 = __half22float2(g1);
            float2 f2 = __half22float2(g2), f3 = __half22float2(g3);
            float w0 = __int_as_float(c0.y), w1 = __int_as_float(c1.y);
            float w2 = __int_as_float(c2.y), w3 = __int_as_float(c3.y);
            ax0 = fmaf(w0, f0.x, ax0); ay0 = fmaf(w0, f0.y, ay0);
            ax1 = fmaf(w1, f1.x, ax1); ay1 = fmaf(w1, f1.y, ay1);
            ax2 = fmaf(w2, f2.x, ax2); ay2 = fmaf(w2, f2.y, ay2);
            ax3 = fmaf(w3, f3.x, ax3); ay3 = fmaf(w3, f3.y, ay3);
            p += 8;
        }
        if (p < e) {        // masked pass covers remaining <8 edges
            int pe0 = p + 0 + q, pe1 = p + 2 + q, pe2 = p + 4 + q, pe3 = p + 6 + q;
            int2 c0 = csr[(pe0 < e) ? pe0 : (e - 1)];
            int2 c1 = csr[(pe1 < e) ? pe1 : (e - 1)];
            int2 c2 = csr[(pe2 < e) ? pe2 : (e - 1)];
            int2 c3 = csr[(pe3 < e) ? pe3 : (e - 1)];
            __half2 g0 = hin[(c0.x << 5) + pp];
            __half2 g1 = hin[(c1.x << 5) + pp];
            __half2 g2 = hin[(c2.x << 5) + pp];
            __half2 g3 = hin[(c3.x << 5) + pp];
            float2 f0 = __half22float2(g0), f1 = __half22float2(g1);
            float2 f2 = __half22float2(g2), f3 = __half22float2(g3);
            float w0 = (pe0 < e) ? __int_as_float(c0.y) : 0.f;
            float w1 = (pe1 < e) ? __int_as_float(c1.y) : 0.f;
            float w2 = (pe2 < e) ? __int_as_float(c2.y) : 0.f;
            float w3 = (pe3 < e) ? __int_as_float(c3.y) : 0.f;
            ax0 = fmaf(w0, f0.x, ax0); ay0 = fmaf(w0, f0.y, ay0);
            ax1 = fmaf(w1, f1.x, ax1); ay1 = fmaf(w1, f1.y, ay1);
            ax2 = fmaf(w2, f2.x, ax2); ay2 = fmaf(w2, f2.y, ay2);
            ax3 = fmaf(w3, f3.x, ax3); ay3 = fmaf(w3, f3.y, ay3);
        }
        float accx = (ax0 + ax1) + (ax2 + ax3);
        float accy = (ay0 + ay1) + (ay2 + ay3);
        // combine even-edge (lanes 0-31) and odd-edge (lanes 32-63) halves
        accx += __shfl_xor(accx, 32);
        accy += __shfl_xor(accy, 32);
        // self-loop + h0, in pair domain (pair index pp)
        float2 s2 = __half22float2(hin[(i << 5) + pp]);
        float2 h02 = __half22float2(h0[(i << 5) + pp]);
        float di = dinv[i];
        accx = di * (accx + di * s2.x);
        accy = di * (accy + di * s2.y);
        float xxp_x = 0.9f * accx + 0.1f * h02.x;
        float xxp_y = 0.9f * accy + 0.1f * h02.y;
        // redistribute pair domain -> lane=feature domain
        float xl = __shfl(xxp_x, lane >> 1);
        float xh = __shfl(xxp_y, lane >> 1);
        float xx = (lane & 1) ? xh : xl;
        float y = 0.f;
#pragma unroll
        for (int k = 0; k < 64; k++) {
            float xk = __shfl(xx, k);
            y += xk * m[k * DH + lane];
        }
        y = fmaxf(y, 0.f);
        float yo = __shfl(y, lane | 1);
        if (!(lane & 1)) {
            __half2 hp = __floats2half2_rn(y, yo);
            hout[(i << 5) + (lane >> 1)] = hp;
        }
    }
}

// out = h @ W_out + b_out  (fp32 output)
__global__ __launch_bounds__(256) void k_out(const __half2* __restrict__ hin,
                                             const float* __restrict__ Wout,
                                             const float* __restrict__ bout,
                                             float* __restrict__ out) {
    __shared__ float m[DH * DH];
    for (int idx = threadIdx.x; idx < DH * DH; idx += 256) m[idx] = Wout[idx];
    __syncthreads();
    int lane = threadIdx.x & 63;
    int wave = threadIdx.x >> 6;
    int gwave = blockIdx.x * 4 + wave;
    int nwaves = gridDim.x * 4;
    float bb = bout[lane];
    for (int i = gwave; i < NN; i += nwaves) {
        float2 f = __half22float2(hin[(i << 5) + (lane >> 1)]);
        float xx = (lane & 1) ? f.y : f.x;
        float y = 0.f;
#pragma unroll
        for (int k = 0; k < 64; k++) {
            float xk = __shfl(xx, k);
            y += xk * m[k * DH + lane];
        }
        out[(size_t)i * DH + lane] = y + bb;
    }
}

// ---------------- launch ----------------

static inline size_t al256(size_t x) { return (x + 255) & ~(size_t)255; }

extern "C" void kernel_launch(void* const* d_in, const int* in_sizes, int n_in,
                              void* d_out, int out_size, void* d_ws, size_t ws_size,
                              hipStream_t stream) {
    const float* x    = (const float*)d_in[0];
    const int*   ei   = (const int*)d_in[1];
    const float* W0   = (const float*)d_in[2];
    const float* b0   = (const float*)d_in[3];
    const float* Ws   = (const float*)d_in[4];
    const float* Wout = (const float*)d_in[5];
    const float* bout = (const float*)d_in[6];
    float* out = (float*)d_out;

    char* w = (char*)d_ws;
    size_t off = 0;
    int* cnt     = (int*)(w + off); off = al256(off + (size_t)NN * 4);
    int* offs    = (int*)(w + off); off = al256(off + ((size_t)NN + 1) * 4);
    int* cursor  = (int*)(w + off); off = al256(off + (size_t)NN * 4);
    int* bsum    = (int*)(w + off); off = al256(off + (size_t)SCAN_B * 4);
    int* boff    = (int*)(w + off); off = al256(off + (size_t)SCAN_B * 4);
    int2* csr    = (int2*)(w + off); off = al256(off + (size_t)NE * 8);
    float* dinv  = (float*)(w + off); off = al256(off + (size_t)NN * 4);
    float* M     = (float*)(w + off); off = al256(off + (size_t)NLAYERS * DH * DH * 4);
    __half2* hA  = (__half2*)(w + off); off = al256(off + (size_t)NN * NP * 4);
    __half2* hB  = (__half2*)(w + off); off = al256(off + (size_t)NN * NP * 4);
    __half2* h0  = (__half2*)(w + off); off = al256(off + (size_t)NN * NP * 4);

    hipMemsetAsync(cnt, 0, (size_t)NN * 4, stream);

    k_count<<<1024, 256, 0, stream>>>(ei, cnt);
    k_dinv<<<(NN + 255) / 256, 256, 0, stream>>>(cnt, dinv);
    k_blocksum<<<NB, SCAN_B, 0, stream>>>(cnt, bsum);
    k_scan_bsum<<<1, SCAN_B, 0, stream>>>(bsum, boff);
    k_scan_final<<<NB, SCAN_B, 0, stream>>>(cnt, boff, offs, cursor);
    k_fill<<<1024, 256, 0, stream>>>(ei, dinv, cursor, csr);
    k_makeM<<<NLAYERS, 256, 0, stream>>>(Ws, M);

    k_layer0<<<2048, 256, 0, stream>>>(x, W0, b0, hA, h0);

    const __half2* cur = hA;
    __half2* nxt = hB;
    for (int l = 0; l < NLAYERS; l++) {
        k_layer<<<2048, 256, 0, stream>>>(cur, h0, M, l, offs, csr, dinv, nxt);
        const __half2* t = nxt;
        nxt = (__half2*)cur;
        cur = (const __half2*)t;
    }
    k_out<<<2048, 256, 0, stream>>>(cur, Wout, bout, out);
}

// Round 4
// 633.177 us; speedup vs baseline: 2.1900x; 1.1805x over previous
//
#include <hip/hip_runtime.h>
#include <hip/hip_fp16.h>
#include <math.h>

#define NN 50000
#define NE 800000
#define DIN 128
#define DH 64
#define NLAYERS 8
#define SCAN_B 256
#define NB ((NN + SCAN_B - 1) / SCAN_B)   // 196
#define NGROUP (NN / 4)                   // 12500 gather groups (4 nodes each)

// ---------------- setup kernels ----------------

__global__ void k_count(const int* __restrict__ ei, int* __restrict__ cnt) {
    int stride = gridDim.x * blockDim.x;
    for (int e = blockIdx.x * blockDim.x + threadIdx.x; e < NE; e += stride) {
        int d = ei[NE + e];
        atomicAdd(&cnt[d], 1);
    }
}

__global__ void k_dinv(const int* __restrict__ cnt, float* __restrict__ dinv) {
    int i = blockIdx.x * blockDim.x + threadIdx.x;
    if (i < NN) dinv[i] = rsqrtf((float)(cnt[i] + 1));   // +1 self-loop
}

__global__ void k_blocksum(const int* __restrict__ cnt, int* __restrict__ bsum) {
    __shared__ int s[SCAN_B];
    int i = blockIdx.x * SCAN_B + threadIdx.x;
    s[threadIdx.x] = (i < NN) ? cnt[i] : 0;
    __syncthreads();
    for (int off = SCAN_B / 2; off > 0; off >>= 1) {
        if (threadIdx.x < off) s[threadIdx.x] += s[threadIdx.x + off];
        __syncthreads();
    }
    if (threadIdx.x == 0) bsum[blockIdx.x] = s[0];
}

__global__ void k_scan_bsum(const int* __restrict__ bsum, int* __restrict__ boff) {
    __shared__ int s[SCAN_B];
    int t = threadIdx.x;
    s[t] = (t < NB) ? bsum[t] : 0;
    __syncthreads();
    for (int off = 1; off < SCAN_B; off <<= 1) {
        int v = (t >= off) ? s[t - off] : 0;
        __syncthreads();
        s[t] += v;
        __syncthreads();
    }
    if (t < NB) boff[t] = (t == 0) ? 0 : s[t - 1];
}

__global__ void k_scan_final(const int* __restrict__ cnt, const int* __restrict__ boff,
                             int* __restrict__ offs, int* __restrict__ cursor) {
    __shared__ int s[SCAN_B];
    int t = threadIdx.x;
    int i = blockIdx.x * SCAN_B + t;
    int v = (i < NN) ? cnt[i] : 0;
    s[t] = v;
    __syncthreads();
    for (int off = 1; off < SCAN_B; off <<= 1) {
        int u = (t >= off) ? s[t - off] : 0;
        __syncthreads();
        s[t] += u;
        __syncthreads();
    }
    if (i < NN) {
        int excl = boff[blockIdx.x] + s[t] - v;
        offs[i] = excl;
        cursor[i] = excl;
        if (i == NN - 1) offs[NN] = excl + v;
    }
}

// packed CSR entry: .x = src node, .y = dinv[src] bits
__global__ void k_fill(const int* __restrict__ ei, const float* __restrict__ dinv,
                       int* __restrict__ cursor, int2* __restrict__ csr) {
    int stride = gridDim.x * blockDim.x;
    for (int e = blockIdx.x * blockDim.x + threadIdx.x; e < NE; e += stride) {
        int s = ei[e];
        int d = ei[NE + e];
        int p = atomicAdd(&cursor[d], 1);
        int2 c;
        c.x = s;
        c.y = __float_as_int(dinv[s]);
        csr[p] = c;
    }
}

// M[l] = (1-beta_l)*I + beta_l*Ws[l]
__global__ void k_makeM(const float* __restrict__ Ws, float* __restrict__ M) {
    int l = blockIdx.x;
    float beta = logf(0.5f / (float)(l + 1) + 1.0f);
    for (int idx = threadIdx.x; idx < DH * DH; idx += blockDim.x) {
        int k = idx >> 6, j = idx & 63;
        float v = beta * Ws[l * DH * DH + idx];
        if (k == j) v += 1.0f - beta;
        M[l * DH * DH + idx] = v;
    }
}

// ---------------- compute kernels ----------------

// plane layout: planeP[node] = 16 half2 (feats 32P .. 32P+31), 64B per row.

// h = relu(x @ W0 + b0) -> h planes + h0 planes
__global__ __launch_bounds__(256) void k_layer0(const float* __restrict__ x,
                                                const float* __restrict__ W0,
                                                const float* __restrict__ b0,
                                                __half2* __restrict__ h0p,
                                                __half2* __restrict__ h1p,
                                                __half2* __restrict__ g0p,
                                                __half2* __restrict__ g1p) {
    __shared__ float w[DIN * DH];   // 32 KB
    for (int idx = threadIdx.x; idx < DIN * DH; idx += 256) w[idx] = W0[idx];
    __syncthreads();
    int lane = threadIdx.x & 63;
    int wave = threadIdx.x >> 6;
    int gwave = blockIdx.x * 4 + wave;
    int nwaves = gridDim.x * 4;
    const float2* x2 = (const float2*)x;
    float bb = b0[lane];
    for (int i = gwave; i < NN; i += nwaves) {
        float2 xp = x2[(size_t)i * 64 + lane];   // feats 2*lane, 2*lane+1
        float a0 = 0.f, a1 = 0.f, a2 = 0.f, a3 = 0.f;
#pragma unroll
        for (int k = 0; k < 128; k += 4) {
            float xk0 = __shfl(xp.x, (k + 0) >> 1);
            float xk1 = __shfl(xp.y, (k + 1) >> 1);
            float xk2 = __shfl(xp.x, (k + 2) >> 1);
            float xk3 = __shfl(xp.y, (k + 3) >> 1);
            a0 = fmaf(xk0, w[(k + 0) * DH + lane], a0);
            a1 = fmaf(xk1, w[(k + 1) * DH + lane], a1);
            a2 = fmaf(xk2, w[(k + 2) * DH + lane], a2);
            a3 = fmaf(xk3, w[(k + 3) * DH + lane], a3);
        }
        float y = fmaxf((a0 + a1) + (a2 + a3) + bb, 0.f);
        float yo = __shfl(y, lane | 1);
        if (!(lane & 1)) {
            __half2 hp = __floats2half2_rn(y, yo);
            int p = lane >> 1;                       // pair index 0..31
            __half2* hb = (p < 16) ? h0p : h1p;
            __half2* gb = (p < 16) ? g0p : g1p;
            hb[i * 16 + (p & 15)] = hp;
            gb[i * 16 + (p & 15)] = hp;
        }
    }
}

// gather for one plane: agg_p[i] = sum_{edges dst=i} dinv[src] * plane_p[src]
// lane mapping: node quarter q = lane>>4 (4 nodes/group), eslot s = (lane>>2)&3
// (4 edges per chunk per node), feat quarter fq = lane&3 (16B of the 64B row).
// One gather instr = 16 half-rows (4 nodes x 4 edges). 4-6 instrs in flight.
__global__ __launch_bounds__(256) void k_gather(const __half2* __restrict__ plane,
                                                const int* __restrict__ offs,
                                                const int2* __restrict__ csr,
                                                __half2* __restrict__ agg) {
    int lane = threadIdx.x & 63;
    int wave = threadIdx.x >> 6;
    int gwave = blockIdx.x * 4 + wave;
    int nwaves = gridDim.x * 4;
    int q = lane >> 4;
    int s = (lane >> 2) & 3;
    int fq = lane & 3;
    const char* pbase = (const char*)plane;
    for (int g = gwave; g < NGROUP; g += nwaves) {
        int node = g * 4 + q;
        int b = offs[node], e = offs[node + 1];
        float2 ac0 = {0.f, 0.f}, ac1 = {0.f, 0.f}, ac2 = {0.f, 0.f}, ac3 = {0.f, 0.f};

        // prologue: chunks 0..3 (16 edge slots per node), masked
#define GATH_CHUNK(C)                                                          \
        {                                                                      \
            int ee = b + 4 * (C) + s;                                          \
            bool v = ee < e;                                                   \
            unsigned long long cv = __builtin_nontemporal_load(                \
                (const unsigned long long*)(csr + (v ? ee : 0)));              \
            int src = (int)(cv & 0xffffffffu);                                 \
            float wv = v ? __int_as_float((int)(cv >> 32)) : 0.f;              \
            int4 gld = *(const int4*)(pbase + ((size_t)src << 6) + (fq << 4)); \
            float2 f0 = __half22float2(*(const __half2*)&gld.x);               \
            float2 f1 = __half22float2(*(const __half2*)&gld.y);               \
            float2 f2 = __half22float2(*(const __half2*)&gld.z);               \
            float2 f3 = __half22float2(*(const __half2*)&gld.w);               \
            ac0.x = fmaf(wv, f0.x, ac0.x); ac0.y = fmaf(wv, f0.y, ac0.y);      \
            ac1.x = fmaf(wv, f1.x, ac1.x); ac1.y = fmaf(wv, f1.y, ac1.y);      \
            ac2.x = fmaf(wv, f2.x, ac2.x); ac2.y = fmaf(wv, f2.y, ac2.y);      \
            ac3.x = fmaf(wv, f3.x, ac3.x); ac3.y = fmaf(wv, f3.y, ac3.y);      \
        }

        GATH_CHUNK(0) GATH_CHUNK(1) GATH_CHUNK(2) GATH_CHUNK(3)
        int c = 4;
        while (__any(b + 4 * c < e)) {
            GATH_CHUNK(c) GATH_CHUNK(c + 1)
            c += 2;
        }
#undef GATH_CHUNK

        // reduce over eslot (lanes l, l^4, l^8, l^12)
#pragma unroll
        for (int off = 4; off <= 8; off <<= 1) {
            ac0.x += __shfl_xor(ac0.x, off); ac0.y += __shfl_xor(ac0.y, off);
            ac1.x += __shfl_xor(ac1.x, off); ac1.y += __shfl_xor(ac1.y, off);
            ac2.x += __shfl_xor(ac2.x, off); ac2.y += __shfl_xor(ac2.y, off);
            ac3.x += __shfl_xor(ac3.x, off); ac3.y += __shfl_xor(ac3.y, off);
        }
        if (s == 0) {
            __half2 o0 = __floats2half2_rn(ac0.x, ac0.y);
            __half2 o1 = __floats2half2_rn(ac1.x, ac1.y);
            __half2 o2 = __floats2half2_rn(ac2.x, ac2.y);
            __half2 o3 = __floats2half2_rn(ac3.x, ac3.y);
            unsigned long long lo = ((unsigned long long)*(unsigned*)&o1 << 32) | *(unsigned*)&o0;
            unsigned long long hi = ((unsigned long long)*(unsigned*)&o3 << 32) | *(unsigned*)&o2;
            char* dst = (char*)agg + ((size_t)node << 6) + (fq << 4);
            __builtin_nontemporal_store(lo, (unsigned long long*)dst);
            __builtin_nontemporal_store(hi, (unsigned long long*)(dst + 8));
        }
    }
}

// blend + 64x64 matvec + relu. 2 nodes per wave (lanes 0-31 node i, 32-63 node i+1),
// each lane owns one feature PAIR (float2 math, m staged in LDS as float2).
__global__ __launch_bounds__(256) void k_matvec(const __half2* __restrict__ agg0,
                                                const __half2* __restrict__ agg1,
                                                const __half2* __restrict__ hin0,
                                                const __half2* __restrict__ hin1,
                                                const __half2* __restrict__ h00,
                                                const __half2* __restrict__ h01,
                                                const float* __restrict__ dinv,
                                                const float* __restrict__ Mall, int layer,
                                                __half2* __restrict__ hout0,
                                                __half2* __restrict__ hout1) {
    __shared__ float2 m2[DH * 32];   // 16 KB, m2[k*32+p] = (M[k][2p], M[k][2p+1])
    const float2* M2 = (const float2*)(Mall + (size_t)layer * DH * DH);
    for (int idx = threadIdx.x; idx < DH * 32; idx += 256) m2[idx] = M2[idx];
    __syncthreads();
    int lane = threadIdx.x & 63;
    int half = lane >> 5;
    int p = lane & 31;
    int pi = p & 15;
    bool lowp = p < 16;
    int wave = threadIdx.x >> 6;
    int gwave = blockIdx.x * 4 + wave;
    int nwaves = gridDim.x * 4;
    for (int ii = gwave; ii < NN / 2; ii += nwaves) {
        int node = ii * 2 + half;
        int idx = node * 16 + pi;
        float2 av = __half22float2(lowp ? agg0[idx] : agg1[idx]);
        float2 sv = __half22float2(lowp ? hin0[idx] : hin1[idx]);
        float2 hv = __half22float2(lowp ? h00[idx] : h01[idx]);
        float di = dinv[node];
        float2 xxp;
        xxp.x = 0.9f * (di * fmaf(di, sv.x, av.x)) + 0.1f * hv.x;
        xxp.y = 0.9f * (di * fmaf(di, sv.y, av.y)) + 0.1f * hv.y;
        float2 ya = {0.f, 0.f}, yb = {0.f, 0.f};
        int base = half << 5;
#pragma unroll
        for (int k = 0; k < 64; k += 2) {
            float xk0 = __shfl(xxp.x, base + (k >> 1));
            float xk1 = __shfl(xxp.y, base + (k >> 1));
            float2 w0 = m2[(k + 0) * 32 + p];
            float2 w1 = m2[(k + 1) * 32 + p];
            ya.x = fmaf(xk0, w0.x, ya.x); ya.y = fmaf(xk0, w0.y, ya.y);
            yb.x = fmaf(xk1, w1.x, yb.x); yb.y = fmaf(xk1, w1.y, yb.y);
        }
        float yx = fmaxf(ya.x + yb.x, 0.f);
        float yy = fmaxf(ya.y + yb.y, 0.f);
        __half2 hp = __floats2half2_rn(yx, yy);
        __half2* ob = lowp ? hout0 : hout1;
        ob[idx] = hp;
    }
}

// out = h @ W_out + b_out (fp32)
__global__ __launch_bounds__(256) void k_out(const __half2* __restrict__ hin0,
                                             const __half2* __restrict__ hin1,
                                             const float* __restrict__ Wout,
                                             const float* __restrict__ bout,
                                             float* __restrict__ out) {
    __shared__ float2 m2[DH * 32];
    const float2* M2 = (const float2*)Wout;
    for (int idx = threadIdx.x; idx < DH * 32; idx += 256) m2[idx] = M2[idx];
    __syncthreads();
    int lane = threadIdx.x & 63;
    int half = lane >> 5;
    int p = lane & 31;
    int pi = p & 15;
    bool lowp = p < 16;
    int wave = threadIdx.x >> 6;
    int gwave = blockIdx.x * 4 + wave;
    int nwaves = gridDim.x * 4;
    float2 bb = ((const float2*)bout)[p];
    for (int ii = gwave; ii < NN / 2; ii += nwaves) {
        int node = ii * 2 + half;
        int idx = node * 16 + pi;
        float2 xxp = __half22float2(lowp ? hin0[idx] : hin1[idx]);
        float2 ya = {0.f, 0.f}, yb = {0.f, 0.f};
        int base = half << 5;
#pragma unroll
        for (int k = 0; k < 64; k += 2) {
            float xk0 = __shfl(xxp.x, base + (k >> 1));
            float xk1 = __shfl(xxp.y, base + (k >> 1));
            float2 w0 = m2[(k + 0) * 32 + p];
            float2 w1 = m2[(k + 1) * 32 + p];
            ya.x = fmaf(xk0, w0.x, ya.x); ya.y = fmaf(xk0, w0.y, ya.y);
            yb.x = fmaf(xk1, w1.x, yb.x); yb.y = fmaf(xk1, w1.y, yb.y);
        }
        float2 yv;
        yv.x = ya.x + yb.x + bb.x;
        yv.y = ya.y + yb.y + bb.y;
        ((float2*)out)[(size_t)node * 32 + p] = yv;
    }
}

// ---------------- launch ----------------

static inline size_t al256(size_t x) { return (x + 255) & ~(size_t)255; }

extern "C" void kernel_launch(void* const* d_in, const int* in_sizes, int n_in,
                              void* d_out, int out_size, void* d_ws, size_t ws_size,
                              hipStream_t stream) {
    const float* x    = (const float*)d_in[0];
    const int*   ei   = (const int*)d_in[1];
    const float* W0   = (const float*)d_in[2];
    const float* b0   = (const float*)d_in[3];
    const float* Ws   = (const float*)d_in[4];
    const float* Wout = (const float*)d_in[5];
    const float* bout = (const float*)d_in[6];
    float* out = (float*)d_out;

    char* w = (char*)d_ws;
    size_t off = 0;
    const size_t PL = (size_t)NN * 16 * sizeof(__half2);   // 3.2 MB plane
    int* cnt     = (int*)(w + off); off = al256(off + (size_t)NN * 4);
    int* offs    = (int*)(w + off); off = al256(off + ((size_t)NN + 1) * 4);
    int* cursor  = (int*)(w + off); off = al256(off + (size_t)NN * 4);
    int* bsum    = (int*)(w + off); off = al256(off + (size_t)SCAN_B * 4);
    int* boff    = (int*)(w + off); off = al256(off + (size_t)SCAN_B * 4);
    int2* csr    = (int2*)(w + off); off = al256(off + (size_t)NE * 8);
    float* dinv  = (float*)(w + off); off = al256(off + (size_t)NN * 4);
    float* M     = (float*)(w + off); off = al256(off + (size_t)NLAYERS * DH * DH * 4);
    __half2* hA0 = (__half2*)(w + off); off = al256(off + PL);
    __half2* hA1 = (__half2*)(w + off); off = al256(off + PL);
    __half2* hB0 = (__half2*)(w + off); off = al256(off + PL);
    __half2* hB1 = (__half2*)(w + off); off = al256(off + PL);
    __half2* g00 = (__half2*)(w + off); off = al256(off + PL);
    __half2* g01 = (__half2*)(w + off); off = al256(off + PL);
    __half2* ag0 = (__half2*)(w + off); off = al256(off + PL);
    __half2* ag1 = (__half2*)(w + off); off = al256(off + PL);

    hipMemsetAsync(cnt, 0, (size_t)NN * 4, stream);

    k_count<<<1024, 256, 0, stream>>>(ei, cnt);
    k_dinv<<<(NN + 255) / 256, 256, 0, stream>>>(cnt, dinv);
    k_blocksum<<<NB, SCAN_B, 0, stream>>>(cnt, bsum);
    k_scan_bsum<<<1, SCAN_B, 0, stream>>>(bsum, boff);
    k_scan_final<<<NB, SCAN_B, 0, stream>>>(cnt, boff, offs, cursor);
    k_fill<<<1024, 256, 0, stream>>>(ei, dinv, cursor, csr);
    k_makeM<<<NLAYERS, 256, 0, stream>>>(Ws, M);

    k_layer0<<<2048, 256, 0, stream>>>(x, W0, b0, hA0, hA1, g00, g01);

    const __half2 *c0 = hA0, *c1 = hA1;
    __half2 *n0 = hB0, *n1 = hB1;
    for (int l = 0; l < NLAYERS; l++) {
        k_gather<<<1024, 256, 0, stream>>>(c0, offs, csr, ag0);
        k_gather<<<1024, 256, 0, stream>>>(c1, offs, csr, ag1);
        k_matvec<<<1024, 256, 0, stream>>>(ag0, ag1, c0, c1, g00, g01,
                                           dinv, M, l, n0, n1);
        const __half2* t0 = n0; const __half2* t1 = n1;
        n0 = (__half2*)c0; n1 = (__half2*)c1;
        c0 = t0; c1 = t1;
    }
    k_out<<<1024, 256, 0, stream>>>(c0, c1, Wout, bout, out);
}

// Round 5
// 398.329 us; speedup vs baseline: 3.4811x; 1.5896x over previous
//
#include <hip/hip_runtime.h>
#include <hip/hip_fp16.h>
#include <math.h>

#define NN 50000
#define NE 800000
#define NLAYERS 8
#define SCAN_B 256
#define NBLK ((NN + SCAN_B - 1) / SCAN_B)   // 196
#define NGROUP (NN / 4)                     // 12500
#define NTILE (NN / 16)                     // 3125

typedef _Float16 f16x8 __attribute__((ext_vector_type(8)));
typedef float f32x4 __attribute__((ext_vector_type(4)));

// ---------------- setup kernels ----------------

__global__ void k_count(const int* __restrict__ ei, int* __restrict__ cnt) {
    int stride = gridDim.x * blockDim.x;
    for (int e = blockIdx.x * blockDim.x + threadIdx.x; e < NE; e += stride) {
        int d = ei[NE + e];
        atomicAdd(&cnt[d], 1);
    }
}

__global__ void k_dinv(const int* __restrict__ cnt, float* __restrict__ dinv,
                       float* __restrict__ rdinv) {
    int i = blockIdx.x * blockDim.x + threadIdx.x;
    if (i < NN) {
        float d = (float)(cnt[i] + 1);   // +1 self-loop
        dinv[i] = rsqrtf(d);
        rdinv[i] = sqrtf(d);
    }
}

__global__ void k_blocksum(const int* __restrict__ cnt, int* __restrict__ bsum) {
    __shared__ int s[SCAN_B];
    int i = blockIdx.x * SCAN_B + threadIdx.x;
    s[threadIdx.x] = (i < NN) ? cnt[i] : 0;
    __syncthreads();
    for (int off = SCAN_B / 2; off > 0; off >>= 1) {
        if (threadIdx.x < off) s[threadIdx.x] += s[threadIdx.x + off];
        __syncthreads();
    }
    if (threadIdx.x == 0) bsum[blockIdx.x] = s[0];
}

__global__ void k_scan_bsum(const int* __restrict__ bsum, int* __restrict__ boff) {
    __shared__ int s[SCAN_B];
    int t = threadIdx.x;
    s[t] = (t < NBLK) ? bsum[t] : 0;
    __syncthreads();
    for (int off = 1; off < SCAN_B; off <<= 1) {
        int v = (t >= off) ? s[t - off] : 0;
        __syncthreads();
        s[t] += v;
        __syncthreads();
    }
    if (t < NBLK) boff[t] = (t == 0) ? 0 : s[t - 1];
}

__global__ void k_scan_final(const int* __restrict__ cnt, const int* __restrict__ boff,
                             int* __restrict__ offs, int* __restrict__ cursor) {
    __shared__ int s[SCAN_B];
    int t = threadIdx.x;
    int i = blockIdx.x * SCAN_B + t;
    int v = (i < NN) ? cnt[i] : 0;
    s[t] = v;
    __syncthreads();
    for (int off = 1; off < SCAN_B; off <<= 1) {
        int u = (t >= off) ? s[t - off] : 0;
        __syncthreads();
        s[t] += u;
        __syncthreads();
    }
    if (i < NN) {
        int excl = boff[blockIdx.x] + s[t] - v;
        offs[i] = excl;
        cursor[i] = excl;
        if (i == NN - 1) offs[NN] = excl + v;
    }
}

// csr entry: src node only (4B); weight folded into pre-scaled p planes
__global__ void k_fill(const int* __restrict__ ei, int* __restrict__ cursor,
                       int* __restrict__ csrs) {
    int stride = gridDim.x * blockDim.x;
    for (int e = blockIdx.x * blockDim.x + threadIdx.x; e < NE; e += stride) {
        int s = ei[e];
        int d = ei[NE + e];
        int p = atomicAdd(&cursor[d], 1);
        csrs[p] = s;
    }
}

// zero row NN (gather target for masked slots) of the 4 p-planes
__global__ void k_zrow(__half2* a, __half2* b, __half2* c, __half2* d) {
    int t = threadIdx.x;
    __half2 z = __floats2half2_rn(0.f, 0.f);
    if (t < 16) a[NN * 16 + t] = z;
    else if (t < 32) b[NN * 16 + (t & 15)] = z;
    else if (t < 48) c[NN * 16 + (t & 15)] = z;
    else d[NN * 16 + (t & 15)] = z;
}

// Pre-rearrange all B-matrices into MFMA fragment order (fp16):
// frag[fid][lane][j] = B[k = kt*32 + (lane>>4)*8 + j][n = nb*16 + (lane&15)]
// fid 0..15: W0 (kt 0-3, nb 0-3); 16..79: M_l = (1-b)I + b*Ws[l] (8 frags/layer);
// 80..87: Wout.
__global__ void k_makefrag(const float* __restrict__ W0, const float* __restrict__ Ws,
                           const float* __restrict__ Wout, __half* __restrict__ frag) {
    int fid = blockIdx.x;
    int lane = threadIdx.x;
    int m = lane & 15, g = lane >> 4;
#pragma unroll
    for (int j = 0; j < 8; j++) {
        float v;
        if (fid < 16) {
            int kt = fid >> 2, nb = fid & 3;
            int k = kt * 32 + g * 8 + j, n = nb * 16 + m;
            v = W0[k * 64 + n];
        } else if (fid < 80) {
            int t = fid - 16;
            int l = t >> 3, kt = (t >> 2) & 1, nb = t & 3;
            float beta = logf(0.5f / (float)(l + 1) + 1.0f);
            int k = kt * 32 + g * 8 + j, n = nb * 16 + m;
            v = beta * Ws[l * 4096 + k * 64 + n] + ((k == n) ? (1.0f - beta) : 0.0f);
        } else {
            int t = fid - 80;
            int kt = t >> 2, nb = t & 3;
            int k = kt * 32 + g * 8 + j, n = nb * 16 + m;
            v = Wout[k * 64 + n];
        }
        frag[fid * 512 + lane * 8 + j] = __float2half(v);
    }
}

// ---------------- compute kernels ----------------
// plane layout: plane[node] = 16 half2 = 64B (32 feats). plane0 = feats 0-31,
// plane1 = feats 32-63. p planes hold dinv[i]*h[i]; h0 planes hold h0 raw.

// h = relu(x @ W0 + b0): MFMA over 16-node tiles, K=128 (4 ktiles).
__global__ __launch_bounds__(256) void k_layer0(const float* __restrict__ x,
        const __half* __restrict__ frag, const float* __restrict__ b0,
        const float* __restrict__ dinv,
        __half2* __restrict__ p0, __half2* __restrict__ p1,
        __half2* __restrict__ h00, __half2* __restrict__ h01) {
    __shared__ __half lds[4][16 * 80];
    int lane = threadIdx.x & 63, wave = threadIdx.x >> 6;
    int gwave = blockIdx.x * 4 + wave, nwaves = gridDim.x * 4;
    int m = lane & 15, g = lane >> 4;
    f16x8 bf[4][4];
    const int4* fb = (const int4*)frag;
#pragma unroll
    for (int kt = 0; kt < 4; kt++)
#pragma unroll
        for (int nb = 0; nb < 4; nb++) {
            int4 r = fb[(kt * 4 + nb) * 64 + lane];
            bf[kt][nb] = *(f16x8*)&r;
        }
    float bb[4];
#pragma unroll
    for (int nb = 0; nb < 4; nb++) bb[nb] = b0[nb * 16 + m];
    __half* L = &lds[wave][0];
    for (int t = gwave; t < NTILE; t += nwaves) {
        int tb = t * 16;
        f32x4 acc[4] = {};
        const float* xrow = x + (size_t)(tb + m) * 128;
#pragma unroll
        for (int kt = 0; kt < 4; kt++) {
            float4 r0 = *(const float4*)(xrow + kt * 32 + g * 8);
            float4 r1 = *(const float4*)(xrow + kt * 32 + g * 8 + 4);
            f16x8 af;
            af[0] = (_Float16)r0.x; af[1] = (_Float16)r0.y;
            af[2] = (_Float16)r0.z; af[3] = (_Float16)r0.w;
            af[4] = (_Float16)r1.x; af[5] = (_Float16)r1.y;
            af[6] = (_Float16)r1.z; af[7] = (_Float16)r1.w;
#pragma unroll
            for (int nb = 0; nb < 4; nb++)
                acc[nb] = __builtin_amdgcn_mfma_f32_16x16x32_f16(af, bf[kt][nb], acc[nb], 0, 0, 0);
        }
#pragma unroll
        for (int nb = 0; nb < 4; nb++)
#pragma unroll
            for (int r = 0; r < 4; r++) {
                int mm = g * 4 + r;
                float y = fmaxf(acc[nb][r] + bb[nb], 0.f);
                L[mm * 80 + nb * 16 + m] = __float2half(y);
            }
        asm volatile("" ::: "memory");
        int n2 = tb + m;
        float dv = dinv[n2];
        int4 lo = *(const int4*)&L[m * 80 + g * 8];        // feats 0-31 quarter
        int4 hi = *(const int4*)&L[m * 80 + 32 + g * 8];   // feats 32-63 quarter
        *(int4*)(h00 + (size_t)n2 * 16 + g * 4) = lo;
        *(int4*)(h01 + (size_t)n2 * 16 + g * 4) = hi;
        int4 slo, shi;
        const __half2* l2 = (const __half2*)&lo; __half2* s2 = (__half2*)&slo;
        const __half2* h2 = (const __half2*)&hi; __half2* t2 = (__half2*)&shi;
#pragma unroll
        for (int u = 0; u < 4; u++) {
            float2 a = __half22float2(l2[u]); s2[u] = __floats2half2_rn(a.x * dv, a.y * dv);
            float2 b = __half22float2(h2[u]); t2[u] = __floats2half2_rn(b.x * dv, b.y * dv);
        }
        *(int4*)(p0 + (size_t)n2 * 16 + g * 4) = slo;
        *(int4*)(p1 + (size_t)n2 * 16 + g * 4) = shi;
        asm volatile("" ::: "memory");
    }
}

// agg_p[i] = sum_{edges dst=i} p_plane[src]   (unweighted, p pre-scaled)
__global__ __launch_bounds__(256) void k_gather(const __half2* __restrict__ plane,
        const int* __restrict__ offs, const int* __restrict__ csrs,
        __half2* __restrict__ agg) {
    int lane = threadIdx.x & 63, wave = threadIdx.x >> 6;
    int gwave = blockIdx.x * 4 + wave, nwaves = gridDim.x * 4;
    int q = lane >> 4, s = (lane >> 2) & 3, fq = lane & 3;
    const char* pbase = (const char*)plane;
    for (int g = gwave; g < NGROUP; g += nwaves) {
        int node = g * 4 + q;
        int b = offs[node], e = offs[node + 1];
        float2 ac0 = {0.f, 0.f}, ac1 = {0.f, 0.f}, ac2 = {0.f, 0.f}, ac3 = {0.f, 0.f};
#define GCH(C) {                                                               \
        int ee = b + 4 * (C) + s;                                              \
        bool v = ee < e;                                                       \
        int src = __builtin_nontemporal_load(csrs + (v ? ee : 0));             \
        src = v ? src : NN;                                                    \
        int4 gld = *(const int4*)(pbase + ((size_t)src << 6) + (fq << 4));     \
        float2 f0 = __half22float2(*(const __half2*)&gld.x);                   \
        float2 f1 = __half22float2(*(const __half2*)&gld.y);                   \
        float2 f2 = __half22float2(*(const __half2*)&gld.z);                   \
        float2 f3 = __half22float2(*(const __half2*)&gld.w);                   \
        ac0.x += f0.x; ac0.y += f0.y; ac1.x += f1.x; ac1.y += f1.y;            \
        ac2.x += f2.x; ac2.y += f2.y; ac3.x += f3.x; ac3.y += f3.y; }
        GCH(0) GCH(1) GCH(2) GCH(3)
        int c = 4;
        while (__any(b + 4 * c < e)) {
            GCH(c) GCH(c + 1)
            c += 2;
        }
#undef GCH
#pragma unroll
        for (int off = 4; off <= 8; off <<= 1) {
            ac0.x += __shfl_xor(ac0.x, off); ac0.y += __shfl_xor(ac0.y, off);
            ac1.x += __shfl_xor(ac1.x, off); ac1.y += __shfl_xor(ac1.y, off);
            ac2.x += __shfl_xor(ac2.x, off); ac2.y += __shfl_xor(ac2.y, off);
            ac3.x += __shfl_xor(ac3.x, off); ac3.y += __shfl_xor(ac3.y, off);
        }
        if (s == 0) {
            __half2 o0 = __floats2half2_rn(ac0.x, ac0.y);
            __half2 o1 = __floats2half2_rn(ac1.x, ac1.y);
            __half2 o2 = __floats2half2_rn(ac2.x, ac2.y);
            __half2 o3 = __floats2half2_rn(ac3.x, ac3.y);
            unsigned long long lo = ((unsigned long long)*(unsigned*)&o1 << 32) | *(unsigned*)&o0;
            unsigned long long hi = ((unsigned long long)*(unsigned*)&o3 << 32) | *(unsigned*)&o2;
            char* dst = (char*)agg + ((size_t)node << 6) + (fq << 4);
            __builtin_nontemporal_store(lo, (unsigned long long*)dst);
            __builtin_nontemporal_store(hi, (unsigned long long*)(dst + 8));
        }
    }
}

// p_out = dinv * relu( (0.9*dinv*(agg+p) + 0.1*h0) @ M_l ), MFMA K=64
__global__ __launch_bounds__(256) void k_matvec(const __half2* __restrict__ ag0,
        const __half2* __restrict__ ag1,
        const __half2* __restrict__ pp0, const __half2* __restrict__ pp1,
        const __half2* __restrict__ h00, const __half2* __restrict__ h01,
        const float* __restrict__ dinv, const __half* __restrict__ frag,
        __half2* __restrict__ po0, __half2* __restrict__ po1) {
    __shared__ __half lds[4][16 * 80];
    int lane = threadIdx.x & 63, wave = threadIdx.x >> 6;
    int gwave = blockIdx.x * 4 + wave, nwaves = gridDim.x * 4;
    int m = lane & 15, g = lane >> 4;
    f16x8 bf[2][4];
    const int4* fb = (const int4*)frag;
#pragma unroll
    for (int kt = 0; kt < 2; kt++)
#pragma unroll
        for (int nb = 0; nb < 4; nb++) {
            int4 r = fb[(kt * 4 + nb) * 64 + lane];
            bf[kt][nb] = *(f16x8*)&r;
        }
    __half* L = &lds[wave][0];
    for (int t = gwave; t < NTILE; t += nwaves) {
        int tb = t * 16;
        float di = dinv[tb + m];
        float c9 = 0.9f * di;
        f32x4 acc[4] = {};
#pragma unroll
        for (int kt = 0; kt < 2; kt++) {
            const __half2* A = kt ? ag1 : ag0;
            const __half2* P = kt ? pp1 : pp0;
            const __half2* H = kt ? h01 : h00;
            size_t base = (size_t)(tb + m) * 16 + g * 4;
            int4 ra = *(const int4*)(A + base);
            int4 rp = *(const int4*)(P + base);
            int4 rh = *(const int4*)(H + base);
            f16x8 af;
#pragma unroll
            for (int u = 0; u < 4; u++) {
                float2 fa = __half22float2(((const __half2*)&ra)[u]);
                float2 fp = __half22float2(((const __half2*)&rp)[u]);
                float2 fh = __half22float2(((const __half2*)&rh)[u]);
                af[2 * u]     = (_Float16)(c9 * (fa.x + fp.x) + 0.1f * fh.x);
                af[2 * u + 1] = (_Float16)(c9 * (fa.y + fp.y) + 0.1f * fh.y);
            }
#pragma unroll
            for (int nb = 0; nb < 4; nb++)
                acc[nb] = __builtin_amdgcn_mfma_f32_16x16x32_f16(af, bf[kt][nb], acc[nb], 0, 0, 0);
        }
        float dvr[4];
#pragma unroll
        for (int r = 0; r < 4; r++) dvr[r] = dinv[tb + g * 4 + r];
#pragma unroll
        for (int nb = 0; nb < 4; nb++)
#pragma unroll
            for (int r = 0; r < 4; r++) {
                int mm = g * 4 + r;
                float y = fmaxf(acc[nb][r], 0.f) * dvr[r];
                L[mm * 80 + nb * 16 + m] = __float2half(y);
            }
        asm volatile("" ::: "memory");
        int n2 = tb + m;
        int4 lo = *(const int4*)&L[m * 80 + g * 8];
        int4 hi = *(const int4*)&L[m * 80 + 32 + g * 8];
        *(int4*)(po0 + (size_t)n2 * 16 + g * 4) = lo;
        *(int4*)(po1 + (size_t)n2 * 16 + g * 4) = hi;
        asm volatile("" ::: "memory");
    }
}

// out = (p*rdinv) @ Wout + bout   (fp32 out)
__global__ __launch_bounds__(256) void k_out(const __half2* __restrict__ pp0,
        const __half2* __restrict__ pp1,
        const float* __restrict__ rdinv, const __half* __restrict__ frag,
        const float* __restrict__ bout, float* __restrict__ out) {
    __shared__ float lds[4][16 * 72];
    int lane = threadIdx.x & 63, wave = threadIdx.x >> 6;
    int gwave = blockIdx.x * 4 + wave, nwaves = gridDim.x * 4;
    int m = lane & 15, g = lane >> 4;
    f16x8 bf[2][4];
    const int4* fb = (const int4*)(frag + 80 * 512);
#pragma unroll
    for (int kt = 0; kt < 2; kt++)
#pragma unroll
        for (int nb = 0; nb < 4; nb++) {
            int4 r = fb[(kt * 4 + nb) * 64 + lane];
            bf[kt][nb] = *(f16x8*)&r;
        }
    float bb[4];
#pragma unroll
    for (int nb = 0; nb < 4; nb++) bb[nb] = bout[nb * 16 + m];
    float* L = &lds[wave][0];
    for (int t = gwave; t < NTILE; t += nwaves) {
        int tb = t * 16;
        float rv = rdinv[tb + m];
        f32x4 acc[4] = {};
#pragma unroll
        for (int kt = 0; kt < 2; kt++) {
            const __half2* P = kt ? pp1 : pp0;
            int4 rp = *(const int4*)(P + (size_t)(tb + m) * 16 + g * 4);
            f16x8 af;
#pragma unroll
            for (int u = 0; u < 4; u++) {
                float2 fp = __half22float2(((const __half2*)&rp)[u]);
                af[2 * u]     = (_Float16)(fp.x * rv);
                af[2 * u + 1] = (_Float16)(fp.y * rv);
            }
#pragma unroll
            for (int nb = 0; nb < 4; nb++)
                acc[nb] = __builtin_amdgcn_mfma_f32_16x16x32_f16(af, bf[kt][nb], acc[nb], 0, 0, 0);
        }
#pragma unroll
        for (int nb = 0; nb < 4; nb++)
#pragma unroll
            for (int r = 0; r < 4; r++)
                L[(g * 4 + r) * 72 + nb * 16 + m] = acc[nb][r] + bb[nb];
        asm volatile("" ::: "memory");
#pragma unroll
        for (int pass = 0; pass < 4; pass++) {
            int nl = pass * 4 + g;
            float4 v = *(const float4*)&L[nl * 72 + m * 4];
            *(float4*)(out + (size_t)(tb + nl) * 64 + m * 4) = v;
        }
        asm volatile("" ::: "memory");
    }
}

// ---------------- launch ----------------

static inline size_t al256(size_t x) { return (x + 255) & ~(size_t)255; }

extern "C" void kernel_launch(void* const* d_in, const int* in_sizes, int n_in,
                              void* d_out, int out_size, void* d_ws, size_t ws_size,
                              hipStream_t stream) {
    const float* x    = (const float*)d_in[0];
    const int*   ei   = (const int*)d_in[1];
    const float* W0   = (const float*)d_in[2];
    const float* b0   = (const float*)d_in[3];
    const float* Ws   = (const float*)d_in[4];
    const float* Wout = (const float*)d_in[5];
    const float* bout = (const float*)d_in[6];
    float* out = (float*)d_out;

    char* w = (char*)d_ws;
    size_t off = 0;
    const size_t PL  = (size_t)(NN + 1) * 16 * sizeof(__half2);  // plane +1 zero row
    const size_t PLS = (size_t)NN * 16 * sizeof(__half2);        // plane, no extra row
    int* cnt     = (int*)(w + off); off = al256(off + (size_t)NN * 4);
    int* offs    = (int*)(w + off); off = al256(off + ((size_t)NN + 1) * 4);
    int* cursor  = (int*)(w + off); off = al256(off + (size_t)NN * 4);
    int* bsum    = (int*)(w + off); off = al256(off + (size_t)SCAN_B * 4);
    int* boff    = (int*)(w + off); off = al256(off + (size_t)SCAN_B * 4);
    int* csrs    = (int*)(w + off); off = al256(off + ((size_t)NE + 8) * 4);
    float* dinv  = (float*)(w + off); off = al256(off + (size_t)NN * 4);
    float* rdinv = (float*)(w + off); off = al256(off + (size_t)NN * 4);
    __half* frag = (__half*)(w + off); off = al256(off + (size_t)88 * 512 * 2);
    __half2* pA0 = (__half2*)(w + off); off = al256(off + PL);
    __half2* pA1 = (__half2*)(w + off); off = al256(off + PL);
    __half2* pB0 = (__half2*)(w + off); off = al256(off + PL);
    __half2* pB1 = (__half2*)(w + off); off = al256(off + PL);
    __half2* g00 = (__half2*)(w + off); off = al256(off + PLS);
    __half2* g01 = (__half2*)(w + off); off = al256(off + PLS);
    __half2* ag0 = (__half2*)(w + off); off = al256(off + PLS);
    __half2* ag1 = (__half2*)(w + off); off = al256(off + PLS);

    hipMemsetAsync(cnt, 0, (size_t)NN * 4, stream);

    k_count<<<1024, 256, 0, stream>>>(ei, cnt);
    k_dinv<<<(NN + 255) / 256, 256, 0, stream>>>(cnt, dinv, rdinv);
    k_blocksum<<<NBLK, SCAN_B, 0, stream>>>(cnt, bsum);
    k_scan_bsum<<<1, SCAN_B, 0, stream>>>(bsum, boff);
    k_scan_final<<<NBLK, SCAN_B, 0, stream>>>(cnt, boff, offs, cursor);
    k_fill<<<1024, 256, 0, stream>>>(ei, cursor, csrs);
    k_zrow<<<1, 64, 0, stream>>>(pA0, pA1, pB0, pB1);
    k_makefrag<<<88, 64, 0, stream>>>(W0, Ws, Wout, frag);

    k_layer0<<<784, 256, 0, stream>>>(x, frag, b0, dinv, pA0, pA1, g00, g01);

    const __half2 *c0 = pA0, *c1 = pA1;
    __half2 *n0 = pB0, *n1 = pB1;
    for (int l = 0; l < NLAYERS; l++) {
        k_gather<<<1024, 256, 0, stream>>>(c0, offs, csrs, ag0);
        k_gather<<<1024, 256, 0, stream>>>(c1, offs, csrs, ag1);
        k_matvec<<<784, 256, 0, stream>>>(ag0, ag1, c0, c1, g00, g01,
                                          dinv, frag + (16 + l * 8) * 512, n0, n1);
        const __half2* t0 = n0; const __half2* t1 = n1;
        n0 = (__half2*)c0; n1 = (__half2*)c1;
        c0 = t0; c1 = t1;
    }
    k_out<<<784, 256, 0, stream>>>(c0, c1, rdinv, frag, bout, out);
}

// Round 6
// 348.738 us; speedup vs baseline: 3.9762x; 1.1422x over previous
//
#include <hip/hip_runtime.h>
#include <hip/hip_fp16.h>
#include <math.h>

#define NN 50000
#define NE 800000
#define NLAYERS 8
#define NGROUP (NN / 4)                     // 12500
#define NTILE (NN / 16)                     // 3125
#define EPB (NE / 256)                      // 3125 edges per hist/part block
#define NBUCKB ((NN + 255) / 256)           // 196 buckets in use
#define BCAP 5120                           // max edges per bucket (lambda~4096)

typedef _Float16 f16x8 __attribute__((ext_vector_type(8)));
typedef float f32x4 __attribute__((ext_vector_type(4)));

// ---------------- CSR build: 4-pass radix partition ----------------

// pass A: per-block histogram of dst>>8
__global__ __launch_bounds__(256) void k_hist(const int* __restrict__ ei,
                                              int* __restrict__ gh) {
    __shared__ int h[256];
    h[threadIdx.x] = 0;
    __syncthreads();
    int base = blockIdx.x * EPB;
    for (int i = threadIdx.x; i < EPB; i += 256) {
        int d = __builtin_nontemporal_load(ei + NE + base + i);
        atomicAdd(&h[d >> 8], 1);
    }
    __syncthreads();
    gh[blockIdx.x * 256 + threadIdx.x] = h[threadIdx.x];
}

// pass B: gh[blk][b] -> global exclusive offset; bbase[b] = bucket start
__global__ void k_scanhist(int* __restrict__ gh, int* __restrict__ bbase) {
    __shared__ int tot[256];
    int t = threadIdx.x;
    int run = 0;
    for (int blk = 0; blk < 256; blk++) {
        int v = gh[blk * 256 + t];
        gh[blk * 256 + t] = run;
        run += v;
    }
    tot[t] = run;
    __syncthreads();
    for (int off = 1; off < 256; off <<= 1) {
        int u = (t >= off) ? tot[t - off] : 0;
        __syncthreads();
        tot[t] += u;
        __syncthreads();
    }
    int ebase = tot[t] - run;   // exclusive bucket base
    for (int blk = 0; blk < 256; blk++) gh[blk * 256 + t] += ebase;
    bbase[t] = ebase;
    if (t == 255) bbase[256] = NE;
}

// pass C: partition (src,dst) pairs into bucket-major order
__global__ __launch_bounds__(256) void k_part(const int* __restrict__ ei,
                                              const int* __restrict__ gh,
                                              int2* __restrict__ part) {
    __shared__ int lcnt[256];
    int t = threadIdx.x;
    lcnt[t] = gh[blockIdx.x * 256 + t];
    __syncthreads();
    int base = blockIdx.x * EPB;
    for (int i = t; i < EPB; i += 256) {
        int s = __builtin_nontemporal_load(ei + base + i);
        int d = __builtin_nontemporal_load(ei + NE + base + i);
        int pos = atomicAdd(&lcnt[d >> 8], 1);
        int2 e; e.x = s; e.y = d;
        part[pos] = e;
    }
}

// pass D: counting-sort each bucket by dst low byte; emit csr, offs, dinv, rdinv
__global__ __launch_bounds__(256) void k_bsort(const int2* __restrict__ part,
                                               const int* __restrict__ bbase,
                                               int* __restrict__ csrs,
                                               int* __restrict__ offs,
                                               float* __restrict__ dinv,
                                               float* __restrict__ rdinv) {
    __shared__ int ssrc[BCAP];
    __shared__ unsigned char sdlo[BCAP];
    __shared__ int dcnt[256], dpos[256], scan[256];
    int b = blockIdx.x, t = threadIdx.x;
    int base0 = bbase[b], base1 = bbase[b + 1];
    int n = base1 - base0;
    if (n > BCAP) n = BCAP;   // never triggers for this input
    dcnt[t] = 0;
    __syncthreads();
    for (int i = t; i < n; i += 256) {
        int2 e = part[base0 + i];
        ssrc[i] = e.x;
        int dlo = e.y & 255;
        sdlo[i] = (unsigned char)dlo;
        atomicAdd(&dcnt[dlo], 1);
    }
    __syncthreads();
    int cnt = dcnt[t];
    scan[t] = cnt;
    __syncthreads();
    for (int off = 1; off < 256; off <<= 1) {
        int u = (t >= off) ? scan[t - off] : 0;
        __syncthreads();
        scan[t] += u;
        __syncthreads();
    }
    int ebase = scan[t] - cnt;
    dpos[t] = ebase;
    __syncthreads();
    // scatter within block-private csr region (single XCD -> L2 write-combine)
    for (int i = t; i < n; i += 256) {
        int d = sdlo[i];
        int r = atomicAdd(&dpos[d], 1);
        csrs[base0 + r] = ssrc[i];
    }
    int gdst = b * 256 + t;
    if (gdst < NN) {
        offs[gdst] = base0 + ebase;
        float dd = (float)(cnt + 1);   // +1 self-loop
        dinv[gdst] = rsqrtf(dd);
        rdinv[gdst] = sqrtf(dd);
    } else if (gdst == NN) {
        offs[NN] = NE;
    }
}

// ---------------- other setup ----------------

// zero row NN (gather target for masked slots) of the 4 p-planes
__global__ void k_zrow(__half2* a, __half2* b, __half2* c, __half2* d) {
    int t = threadIdx.x;
    __half2 z = __floats2half2_rn(0.f, 0.f);
    if (t < 16) a[NN * 16 + t] = z;
    else if (t < 32) b[NN * 16 + (t & 15)] = z;
    else if (t < 48) c[NN * 16 + (t & 15)] = z;
    else d[NN * 16 + (t & 15)] = z;
}

// Pre-rearrange all B-matrices into MFMA fragment order (fp16):
// frag[fid][lane][j] = B[k = kt*32 + (lane>>4)*8 + j][n = nb*16 + (lane&15)]
// fid 0..15: W0; 16..79: M_l = (1-b)I + b*Ws[l]; 80..87: Wout.
__global__ void k_makefrag(const float* __restrict__ W0, const float* __restrict__ Ws,
                           const float* __restrict__ Wout, __half* __restrict__ frag) {
    int fid = blockIdx.x;
    int lane = threadIdx.x;
    int m = lane & 15, g = lane >> 4;
#pragma unroll
    for (int j = 0; j < 8; j++) {
        float v;
        if (fid < 16) {
            int kt = fid >> 2, nb = fid & 3;
            int k = kt * 32 + g * 8 + j, n = nb * 16 + m;
            v = W0[k * 64 + n];
        } else if (fid < 80) {
            int t = fid - 16;
            int l = t >> 3, kt = (t >> 2) & 1, nb = t & 3;
            float beta = logf(0.5f / (float)(l + 1) + 1.0f);
            int k = kt * 32 + g * 8 + j, n = nb * 16 + m;
            v = beta * Ws[l * 4096 + k * 64 + n] + ((k == n) ? (1.0f - beta) : 0.0f);
        } else {
            int t = fid - 80;
            int kt = t >> 2, nb = t & 3;
            int k = kt * 32 + g * 8 + j, n = nb * 16 + m;
            v = Wout[k * 64 + n];
        }
        frag[fid * 512 + lane * 8 + j] = __float2half(v);
    }
}

// ---------------- compute kernels ----------------
// plane layout: plane[node] = 16 half2 = 64B (32 feats). plane0 = feats 0-31,
// plane1 = feats 32-63. p planes hold dinv[i]*h[i]; h0 planes hold h0 raw.

// h = relu(x @ W0 + b0): MFMA over 16-node tiles, K=128 (4 ktiles).
__global__ __launch_bounds__(256) void k_layer0(const float* __restrict__ x,
        const __half* __restrict__ frag, const float* __restrict__ b0,
        const float* __restrict__ dinv,
        __half2* __restrict__ p0, __half2* __restrict__ p1,
        __half2* __restrict__ h00, __half2* __restrict__ h01) {
    __shared__ __half lds[4][16 * 80];
    int lane = threadIdx.x & 63, wave = threadIdx.x >> 6;
    int gwave = blockIdx.x * 4 + wave, nwaves = gridDim.x * 4;
    int m = lane & 15, g = lane >> 4;
    f16x8 bf[4][4];
    const int4* fb = (const int4*)frag;
#pragma unroll
    for (int kt = 0; kt < 4; kt++)
#pragma unroll
        for (int nb = 0; nb < 4; nb++) {
            int4 r = fb[(kt * 4 + nb) * 64 + lane];
            bf[kt][nb] = *(f16x8*)&r;
        }
    float bb[4];
#pragma unroll
    for (int nb = 0; nb < 4; nb++) bb[nb] = b0[nb * 16 + m];
    __half* L = &lds[wave][0];
    for (int t = gwave; t < NTILE; t += nwaves) {
        int tb = t * 16;
        f32x4 acc[4] = {};
        const float* xrow = x + (size_t)(tb + m) * 128;
#pragma unroll
        for (int kt = 0; kt < 4; kt++) {
            float4 r0 = *(const float4*)(xrow + kt * 32 + g * 8);
            float4 r1 = *(const float4*)(xrow + kt * 32 + g * 8 + 4);
            f16x8 af;
            af[0] = (_Float16)r0.x; af[1] = (_Float16)r0.y;
            af[2] = (_Float16)r0.z; af[3] = (_Float16)r0.w;
            af[4] = (_Float16)r1.x; af[5] = (_Float16)r1.y;
            af[6] = (_Float16)r1.z; af[7] = (_Float16)r1.w;
#pragma unroll
            for (int nb = 0; nb < 4; nb++)
                acc[nb] = __builtin_amdgcn_mfma_f32_16x16x32_f16(af, bf[kt][nb], acc[nb], 0, 0, 0);
        }
#pragma unroll
        for (int nb = 0; nb < 4; nb++)
#pragma unroll
            for (int r = 0; r < 4; r++) {
                int mm = g * 4 + r;
                float y = fmaxf(acc[nb][r] + bb[nb], 0.f);
                L[mm * 80 + nb * 16 + m] = __float2half(y);
            }
        asm volatile("" ::: "memory");
        int n2 = tb + m;
        float dv = dinv[n2];
        int4 lo = *(const int4*)&L[m * 80 + g * 8];        // feats 0-31 quarter
        int4 hi = *(const int4*)&L[m * 80 + 32 + g * 8];   // feats 32-63 quarter
        *(int4*)(h00 + (size_t)n2 * 16 + g * 4) = lo;
        *(int4*)(h01 + (size_t)n2 * 16 + g * 4) = hi;
        int4 slo, shi;
        const __half2* l2 = (const __half2*)&lo; __half2* s2 = (__half2*)&slo;
        const __half2* h2 = (const __half2*)&hi; __half2* t2 = (__half2*)&shi;
#pragma unroll
        for (int u = 0; u < 4; u++) {
            float2 a = __half22float2(l2[u]); s2[u] = __floats2half2_rn(a.x * dv, a.y * dv);
            float2 b = __half22float2(h2[u]); t2[u] = __floats2half2_rn(b.x * dv, b.y * dv);
        }
        *(int4*)(p0 + (size_t)n2 * 16 + g * 4) = slo;
        *(int4*)(p1 + (size_t)n2 * 16 + g * 4) = shi;
        asm volatile("" ::: "memory");
    }
}

// agg_p[i] = sum_{edges dst=i} p_plane[src]   (unweighted, p pre-scaled)
__global__ __launch_bounds__(256) void k_gather(const __half2* __restrict__ plane,
        const int* __restrict__ offs, const int* __restrict__ csrs,
        __half2* __restrict__ agg) {
    int lane = threadIdx.x & 63, wave = threadIdx.x >> 6;
    int gwave = blockIdx.x * 4 + wave, nwaves = gridDim.x * 4;
    int q = lane >> 4, s = (lane >> 2) & 3, fq = lane & 3;
    const char* pbase = (const char*)plane;
    for (int g = gwave; g < NGROUP; g += nwaves) {
        int node = g * 4 + q;
        int b = offs[node], e = offs[node + 1];
        float2 ac0 = {0.f, 0.f}, ac1 = {0.f, 0.f}, ac2 = {0.f, 0.f}, ac3 = {0.f, 0.f};
#define GCH(C) {                                                               \
        int ee = b + 4 * (C) + s;                                              \
        bool v = ee < e;                                                       \
        int src = __builtin_nontemporal_load(csrs + (v ? ee : 0));             \
        src = v ? src : NN;                                                    \
        int4 gld = *(const int4*)(pbase + ((size_t)src << 6) + (fq << 4));     \
        float2 f0 = __half22float2(*(const __half2*)&gld.x);                   \
        float2 f1 = __half22float2(*(const __half2*)&gld.y);                   \
        float2 f2 = __half22float2(*(const __half2*)&gld.z);                   \
        float2 f3 = __half22float2(*(const __half2*)&gld.w);                   \
        ac0.x += f0.x; ac0.y += f0.y; ac1.x += f1.x; ac1.y += f1.y;            \
        ac2.x += f2.x; ac2.y += f2.y; ac3.x += f3.x; ac3.y += f3.y; }
        GCH(0) GCH(1) GCH(2) GCH(3)
        int c = 4;
        while (__any(b + 4 * c < e)) {
            GCH(c) GCH(c + 1)
            c += 2;
        }
#undef GCH
#pragma unroll
        for (int off = 4; off <= 8; off <<= 1) {
            ac0.x += __shfl_xor(ac0.x, off); ac0.y += __shfl_xor(ac0.y, off);
            ac1.x += __shfl_xor(ac1.x, off); ac1.y += __shfl_xor(ac1.y, off);
            ac2.x += __shfl_xor(ac2.x, off); ac2.y += __shfl_xor(ac2.y, off);
            ac3.x += __shfl_xor(ac3.x, off); ac3.y += __shfl_xor(ac3.y, off);
        }
        if (s == 0) {
            __half2 o0 = __floats2half2_rn(ac0.x, ac0.y);
            __half2 o1 = __floats2half2_rn(ac1.x, ac1.y);
            __half2 o2 = __floats2half2_rn(ac2.x, ac2.y);
            __half2 o3 = __floats2half2_rn(ac3.x, ac3.y);
            unsigned long long lo = ((unsigned long long)*(unsigned*)&o1 << 32) | *(unsigned*)&o0;
            unsigned long long hi = ((unsigned long long)*(unsigned*)&o3 << 32) | *(unsigned*)&o2;
            char* dst = (char*)agg + ((size_t)node << 6) + (fq << 4);
            __builtin_nontemporal_store(lo, (unsigned long long*)dst);
            __builtin_nontemporal_store(hi, (unsigned long long*)(dst + 8));
        }
    }
}

// p_out = dinv * relu( (0.9*dinv*(agg+p) + 0.1*h0) @ M_l ), MFMA K=64
__global__ __launch_bounds__(256) void k_matvec(const __half2* __restrict__ ag0,
        const __half2* __restrict__ ag1,
        const __half2* __restrict__ pp0, const __half2* __restrict__ pp1,
        const __half2* __restrict__ h00, const __half2* __restrict__ h01,
        const float* __restrict__ dinv, const __half* __restrict__ frag,
        __half2* __restrict__ po0, __half2* __restrict__ po1) {
    __shared__ __half lds[4][16 * 80];
    int lane = threadIdx.x & 63, wave = threadIdx.x >> 6;
    int gwave = blockIdx.x * 4 + wave, nwaves = gridDim.x * 4;
    int m = lane & 15, g = lane >> 4;
    f16x8 bf[2][4];
    const int4* fb = (const int4*)frag;
#pragma unroll
    for (int kt = 0; kt < 2; kt++)
#pragma unroll
        for (int nb = 0; nb < 4; nb++) {
            int4 r = fb[(kt * 4 + nb) * 64 + lane];
            bf[kt][nb] = *(f16x8*)&r;
        }
    __half* L = &lds[wave][0];
    for (int t = gwave; t < NTILE; t += nwaves) {
        int tb = t * 16;
        float di = dinv[tb + m];
        float c9 = 0.9f * di;
        f32x4 acc[4] = {};
#pragma unroll
        for (int kt = 0; kt < 2; kt++) {
            const __half2* A = kt ? ag1 : ag0;
            const __half2* P = kt ? pp1 : pp0;
            const __half2* H = kt ? h01 : h00;
            size_t base = (size_t)(tb + m) * 16 + g * 4;
            int4 ra = *(const int4*)(A + base);
            int4 rp = *(const int4*)(P + base);
            int4 rh = *(const int4*)(H + base);
            f16x8 af;
#pragma unroll
            for (int u = 0; u < 4; u++) {
                float2 fa = __half22float2(((const __half2*)&ra)[u]);
                float2 fp = __half22float2(((const __half2*)&rp)[u]);
                float2 fh = __half22float2(((const __half2*)&rh)[u]);
                af[2 * u]     = (_Float16)(c9 * (fa.x + fp.x) + 0.1f * fh.x);
                af[2 * u + 1] = (_Float16)(c9 * (fa.y + fp.y) + 0.1f * fh.y);
            }
#pragma unroll
            for (int nb = 0; nb < 4; nb++)
                acc[nb] = __builtin_amdgcn_mfma_f32_16x16x32_f16(af, bf[kt][nb], acc[nb], 0, 0, 0);
        }
        float dvr[4];
#pragma unroll
        for (int r = 0; r < 4; r++) dvr[r] = dinv[tb + g * 4 + r];
#pragma unroll
        for (int nb = 0; nb < 4; nb++)
#pragma unroll
            for (int r = 0; r < 4; r++) {
                int mm = g * 4 + r;
                float y = fmaxf(acc[nb][r], 0.f) * dvr[r];
                L[mm * 80 + nb * 16 + m] = __float2half(y);
            }
        asm volatile("" ::: "memory");
        int n2 = tb + m;
        int4 lo = *(const int4*)&L[m * 80 + g * 8];
        int4 hi = *(const int4*)&L[m * 80 + 32 + g * 8];
        *(int4*)(po0 + (size_t)n2 * 16 + g * 4) = lo;
        *(int4*)(po1 + (size_t)n2 * 16 + g * 4) = hi;
        asm volatile("" ::: "memory");
    }
}

// out = (p*rdinv) @ Wout + bout   (fp32 out)
__global__ __launch_bounds__(256) void k_out(const __half2* __restrict__ pp0,
        const __half2* __restrict__ pp1,
        const float* __restrict__ rdinv, const __half* __restrict__ frag,
        const float* __restrict__ bout, float* __restrict__ out) {
    __shared__ float lds[4][16 * 72];
    int lane = threadIdx.x & 63, wave = threadIdx.x >> 6;
    int gwave = blockIdx.x * 4 + wave, nwaves = gridDim.x * 4;
    int m = lane & 15, g = lane >> 4;
    f16x8 bf[2][4];
    const int4* fb = (const int4*)(frag + 80 * 512);
#pragma unroll
    for (int kt = 0; kt < 2; kt++)
#pragma unroll
        for (int nb = 0; nb < 4; nb++) {
            int4 r = fb[(kt * 4 + nb) * 64 + lane];
            bf[kt][nb] = *(f16x8*)&r;
        }
    float bb[4];
#pragma unroll
    for (int nb = 0; nb < 4; nb++) bb[nb] = bout[nb * 16 + m];
    float* L = &lds[wave][0];
    for (int t = gwave; t < NTILE; t += nwaves) {
        int tb = t * 16;
        float rv = rdinv[tb + m];
        f32x4 acc[4] = {};
#pragma unroll
        for (int kt = 0; kt < 2; kt++) {
            const __half2* P = kt ? pp1 : pp0;
            int4 rp = *(const int4*)(P + (size_t)(tb + m) * 16 + g * 4);
            f16x8 af;
#pragma unroll
            for (int u = 0; u < 4; u++) {
                float2 fp = __half22float2(((const __half2*)&rp)[u]);
                af[2 * u]     = (_Float16)(fp.x * rv);
                af[2 * u + 1] = (_Float16)(fp.y * rv);
            }
#pragma unroll
            for (int nb = 0; nb < 4; nb++)
                acc[nb] = __builtin_amdgcn_mfma_f32_16x16x32_f16(af, bf[kt][nb], acc[nb], 0, 0, 0);
        }
#pragma unroll
        for (int nb = 0; nb < 4; nb++)
#pragma unroll
            for (int r = 0; r < 4; r++)
                L[(g * 4 + r) * 72 + nb * 16 + m] = acc[nb][r] + bb[nb];
        asm volatile("" ::: "memory");
#pragma unroll
        for (int pass = 0; pass < 4; pass++) {
            int nl = pass * 4 + g;
            float4 v = *(const float4*)&L[nl * 72 + m * 4];
            *(float4*)(out + (size_t)(tb + nl) * 64 + m * 4) = v;
        }
        asm volatile("" ::: "memory");
    }
}

// ---------------- launch ----------------

static inline size_t al256(size_t x) { return (x + 255) & ~(size_t)255; }

extern "C" void kernel_launch(void* const* d_in, const int* in_sizes, int n_in,
                              void* d_out, int out_size, void* d_ws, size_t ws_size,
                              hipStream_t stream) {
    const float* x    = (const float*)d_in[0];
    const int*   ei   = (const int*)d_in[1];
    const float* W0   = (const float*)d_in[2];
    const float* b0   = (const float*)d_in[3];
    const float* Ws   = (const float*)d_in[4];
    const float* Wout = (const float*)d_in[5];
    const float* bout = (const float*)d_in[6];
    float* out = (float*)d_out;

    char* w = (char*)d_ws;
    size_t off = 0;
    const size_t PL  = (size_t)(NN + 1) * 16 * sizeof(__half2);  // plane +1 zero row
    const size_t PLS = (size_t)NN * 16 * sizeof(__half2);        // plane, no extra row
    int* gh      = (int*)(w + off); off = al256(off + (size_t)256 * 256 * 4);
    int* bbase   = (int*)(w + off); off = al256(off + (size_t)257 * 4);
    int2* part   = (int2*)(w + off); off = al256(off + (size_t)NE * 8);
    int* csrs    = (int*)(w + off); off = al256(off + ((size_t)NE + 8) * 4);
    int* offs    = (int*)(w + off); off = al256(off + ((size_t)NN + 1) * 4);
    float* dinv  = (float*)(w + off); off = al256(off + (size_t)NN * 4);
    float* rdinv = (float*)(w + off); off = al256(off + (size_t)NN * 4);
    __half* frag = (__half*)(w + off); off = al256(off + (size_t)88 * 512 * 2);
    __half2* pA0 = (__half2*)(w + off); off = al256(off + PL);
    __half2* pA1 = (__half2*)(w + off); off = al256(off + PL);
    __half2* pB0 = (__half2*)(w + off); off = al256(off + PL);
    __half2* pB1 = (__half2*)(w + off); off = al256(off + PL);
    __half2* g00 = (__half2*)(w + off); off = al256(off + PLS);
    __half2* g01 = (__half2*)(w + off); off = al256(off + PLS);
    __half2* ag0 = (__half2*)(w + off); off = al256(off + PLS);
    __half2* ag1 = (__half2*)(w + off); off = al256(off + PLS);

    k_hist<<<256, 256, 0, stream>>>(ei, gh);
    k_scanhist<<<1, 256, 0, stream>>>(gh, bbase);
    k_part<<<256, 256, 0, stream>>>(ei, gh, part);
    k_bsort<<<NBUCKB, 256, 0, stream>>>(part, bbase, csrs, offs, dinv, rdinv);
    k_zrow<<<1, 64, 0, stream>>>(pA0, pA1, pB0, pB1);
    k_makefrag<<<88, 64, 0, stream>>>(W0, Ws, Wout, frag);

    k_layer0<<<784, 256, 0, stream>>>(x, frag, b0, dinv, pA0, pA1, g00, g01);

    const __half2 *c0 = pA0, *c1 = pA1;
    __half2 *n0 = pB0, *n1 = pB1;
    for (int l = 0; l < NLAYERS; l++) {
        k_gather<<<1024, 256, 0, stream>>>(c0, offs, csrs, ag0);
        k_gather<<<1024, 256, 0, stream>>>(c1, offs, csrs, ag1);
        k_matvec<<<784, 256, 0, stream>>>(ag0, ag1, c0, c1, g00, g01,
                                          dinv, frag + (16 + l * 8) * 512, n0, n1);
        const __half2* t0 = n0; const __half2* t1 = n1;
        n0 = (__half2*)c0; n1 = (__half2*)c1;
        c0 = t0; c1 = t1;
    }
    k_out<<<784, 256, 0, stream>>>(c0, c1, rdinv, frag, bout, out);
}

// Round 7
// 287.786 us; speedup vs baseline: 4.8183x; 1.2118x over previous
//
#include <hip/hip_runtime.h>
#include <hip/hip_fp16.h>
#include <math.h>

#define NN 50000
#define NE 800000
#define NLAYERS 8
#define NGROUP (NN / 4)                     // 12500
#define NTILE (NN / 16)                     // 3125
#define EPB (NE / 256)                      // 3125 edges per hist/part block
#define NBUCKB ((NN + 255) / 256)           // 196 buckets in use
#define BCAP 5120                           // max edges per bucket (lambda~4096)

typedef _Float16 f16x8 __attribute__((ext_vector_type(8)));
typedef float f32x4 __attribute__((ext_vector_type(4)));

// ---------------- CSR build: 4-pass radix partition ----------------

// pass A: per-block histogram of dst>>8
__global__ __launch_bounds__(256) void k_hist(const int* __restrict__ ei,
                                              int* __restrict__ gh) {
    __shared__ int h[256];
    h[threadIdx.x] = 0;
    __syncthreads();
    int base = blockIdx.x * EPB;
    for (int i = threadIdx.x; i < EPB; i += 256) {
        int d = __builtin_nontemporal_load(ei + NE + base + i);
        atomicAdd(&h[d >> 8], 1);
    }
    __syncthreads();
    gh[blockIdx.x * 256 + threadIdx.x] = h[threadIdx.x];
}

// pass B: gh[blk][b] -> global exclusive offset; bbase[b] = bucket start
__global__ void k_scanhist(int* __restrict__ gh, int* __restrict__ bbase) {
    __shared__ int tot[256];
    int t = threadIdx.x;
    int run = 0;
    for (int blk = 0; blk < 256; blk++) {
        int v = gh[blk * 256 + t];
        gh[blk * 256 + t] = run;
        run += v;
    }
    tot[t] = run;
    __syncthreads();
    for (int off = 1; off < 256; off <<= 1) {
        int u = (t >= off) ? tot[t - off] : 0;
        __syncthreads();
        tot[t] += u;
        __syncthreads();
    }
    int ebase = tot[t] - run;   // exclusive bucket base
    for (int blk = 0; blk < 256; blk++) gh[blk * 256 + t] += ebase;
    bbase[t] = ebase;
    if (t == 255) bbase[256] = NE;
}

// pass C: partition (src,dst) pairs into bucket-major order
__global__ __launch_bounds__(256) void k_part(const int* __restrict__ ei,
                                              const int* __restrict__ gh,
                                              int2* __restrict__ part) {
    __shared__ int lcnt[256];
    int t = threadIdx.x;
    lcnt[t] = gh[blockIdx.x * 256 + t];
    __syncthreads();
    int base = blockIdx.x * EPB;
    for (int i = t; i < EPB; i += 256) {
        int s = __builtin_nontemporal_load(ei + base + i);
        int d = __builtin_nontemporal_load(ei + NE + base + i);
        int pos = atomicAdd(&lcnt[d >> 8], 1);
        int2 e; e.x = s; e.y = d;
        part[pos] = e;
    }
}

// pass D: counting-sort each bucket by dst low byte; emit csr, offs, dinv, rdinv
__global__ __launch_bounds__(256) void k_bsort(const int2* __restrict__ part,
                                               const int* __restrict__ bbase,
                                               int* __restrict__ csrs,
                                               int* __restrict__ offs,
                                               float* __restrict__ dinv,
                                               float* __restrict__ rdinv) {
    __shared__ int ssrc[BCAP];
    __shared__ unsigned char sdlo[BCAP];
    __shared__ int dcnt[256], dpos[256], scan[256];
    int b = blockIdx.x, t = threadIdx.x;
    int base0 = bbase[b], base1 = bbase[b + 1];
    int n = base1 - base0;
    if (n > BCAP) n = BCAP;   // never triggers for this input
    dcnt[t] = 0;
    __syncthreads();
    for (int i = t; i < n; i += 256) {
        int2 e = part[base0 + i];
        ssrc[i] = e.x;
        int dlo = e.y & 255;
        sdlo[i] = (unsigned char)dlo;
        atomicAdd(&dcnt[dlo], 1);
    }
    __syncthreads();
    int cnt = dcnt[t];
    scan[t] = cnt;
    __syncthreads();
    for (int off = 1; off < 256; off <<= 1) {
        int u = (t >= off) ? scan[t - off] : 0;
        __syncthreads();
        scan[t] += u;
        __syncthreads();
    }
    int ebase = scan[t] - cnt;
    dpos[t] = ebase;
    __syncthreads();
    // scatter within block-private csr region (single XCD -> L2 write-combine)
    for (int i = t; i < n; i += 256) {
        int d = sdlo[i];
        int r = atomicAdd(&dpos[d], 1);
        csrs[base0 + r] = ssrc[i];
    }
    int gdst = b * 256 + t;
    if (gdst < NN) {
        offs[gdst] = base0 + ebase;
        float dd = (float)(cnt + 1);   // +1 self-loop
        dinv[gdst] = rsqrtf(dd);
        rdinv[gdst] = sqrtf(dd);
    } else if (gdst == NN) {
        offs[NN] = NE;
    }
}

// ---------------- other setup ----------------

// zero row NN (gather target for masked slots) of the 4 p-planes
__global__ void k_zrow(__half2* a, __half2* b, __half2* c, __half2* d) {
    int t = threadIdx.x;
    __half2 z = __floats2half2_rn(0.f, 0.f);
    if (t < 16) a[NN * 16 + t] = z;
    else if (t < 32) b[NN * 16 + (t & 15)] = z;
    else if (t < 48) c[NN * 16 + (t & 15)] = z;
    else d[NN * 16 + (t & 15)] = z;
}

// Pre-rearrange all B-matrices into MFMA fragment order (fp16):
// frag[fid][lane][j] = B[k = kt*32 + (lane>>4)*8 + j][n = nb*16 + (lane&15)]
// fid 0..15: W0; 16..79: M_l = (1-b)I + b*Ws[l]; 80..87: Wout.
__global__ void k_makefrag(const float* __restrict__ W0, const float* __restrict__ Ws,
                           const float* __restrict__ Wout, __half* __restrict__ frag) {
    int fid = blockIdx.x;
    int lane = threadIdx.x;
    int m = lane & 15, g = lane >> 4;
#pragma unroll
    for (int j = 0; j < 8; j++) {
        float v;
        if (fid < 16) {
            int kt = fid >> 2, nb = fid & 3;
            int k = kt * 32 + g * 8 + j, n = nb * 16 + m;
            v = W0[k * 64 + n];
        } else if (fid < 80) {
            int t = fid - 16;
            int l = t >> 3, kt = (t >> 2) & 1, nb = t & 3;
            float beta = logf(0.5f / (float)(l + 1) + 1.0f);
            int k = kt * 32 + g * 8 + j, n = nb * 16 + m;
            v = beta * Ws[l * 4096 + k * 64 + n] + ((k == n) ? (1.0f - beta) : 0.0f);
        } else {
            int t = fid - 80;
            int kt = t >> 2, nb = t & 3;
            int k = kt * 32 + g * 8 + j, n = nb * 16 + m;
            v = Wout[k * 64 + n];
        }
        frag[fid * 512 + lane * 8 + j] = __float2half(v);
    }
}

// ---------------- compute kernels ----------------
// plane layout: plane[node] = 16 half2 = 64B (32 feats). plane0 = feats 0-31,
// plane1 = feats 32-63. p planes hold dinv[i]*h[i]; h0 planes hold h0 raw.

// h = relu(x @ W0 + b0): MFMA over 16-node tiles, K=128 (4 ktiles).
__global__ __launch_bounds__(256) void k_layer0(const float* __restrict__ x,
        const __half* __restrict__ frag, const float* __restrict__ b0,
        const float* __restrict__ dinv,
        __half2* __restrict__ p0, __half2* __restrict__ p1,
        __half2* __restrict__ h00, __half2* __restrict__ h01) {
    __shared__ __half lds[4][16 * 80];
    int lane = threadIdx.x & 63, wave = threadIdx.x >> 6;
    int gwave = blockIdx.x * 4 + wave, nwaves = gridDim.x * 4;
    int m = lane & 15, g = lane >> 4;
    f16x8 bf[4][4];
    const int4* fb = (const int4*)frag;
#pragma unroll
    for (int kt = 0; kt < 4; kt++)
#pragma unroll
        for (int nb = 0; nb < 4; nb++) {
            int4 r = fb[(kt * 4 + nb) * 64 + lane];
            bf[kt][nb] = *(f16x8*)&r;
        }
    float bb[4];
#pragma unroll
    for (int nb = 0; nb < 4; nb++) bb[nb] = b0[nb * 16 + m];
    __half* L = &lds[wave][0];
    for (int t = gwave; t < NTILE; t += nwaves) {
        int tb = t * 16;
        f32x4 acc[4] = {};
        const float* xrow = x + (size_t)(tb + m) * 128;
#pragma unroll
        for (int kt = 0; kt < 4; kt++) {
            float4 r0 = *(const float4*)(xrow + kt * 32 + g * 8);
            float4 r1 = *(const float4*)(xrow + kt * 32 + g * 8 + 4);
            f16x8 af;
            af[0] = (_Float16)r0.x; af[1] = (_Float16)r0.y;
            af[2] = (_Float16)r0.z; af[3] = (_Float16)r0.w;
            af[4] = (_Float16)r1.x; af[5] = (_Float16)r1.y;
            af[6] = (_Float16)r1.z; af[7] = (_Float16)r1.w;
#pragma unroll
            for (int nb = 0; nb < 4; nb++)
                acc[nb] = __builtin_amdgcn_mfma_f32_16x16x32_f16(af, bf[kt][nb], acc[nb], 0, 0, 0);
        }
#pragma unroll
        for (int nb = 0; nb < 4; nb++)
#pragma unroll
            for (int r = 0; r < 4; r++) {
                int mm = g * 4 + r;
                float y = fmaxf(acc[nb][r] + bb[nb], 0.f);
                L[mm * 80 + nb * 16 + m] = __float2half(y);
            }
        asm volatile("" ::: "memory");
        int n2 = tb + m;
        float dv = dinv[n2];
        int4 lo = *(const int4*)&L[m * 80 + g * 8];        // feats 0-31 quarter
        int4 hi = *(const int4*)&L[m * 80 + 32 + g * 8];   // feats 32-63 quarter
        *(int4*)(h00 + (size_t)n2 * 16 + g * 4) = lo;
        *(int4*)(h01 + (size_t)n2 * 16 + g * 4) = hi;
        int4 slo, shi;
        const __half2* l2 = (const __half2*)&lo; __half2* s2 = (__half2*)&slo;
        const __half2* h2 = (const __half2*)&hi; __half2* t2 = (__half2*)&shi;
#pragma unroll
        for (int u = 0; u < 4; u++) {
            float2 a = __half22float2(l2[u]); s2[u] = __floats2half2_rn(a.x * dv, a.y * dv);
            float2 b = __half22float2(h2[u]); t2[u] = __floats2half2_rn(b.x * dv, b.y * dv);
        }
        *(int4*)(p0 + (size_t)n2 * 16 + g * 4) = slo;
        *(int4*)(p1 + (size_t)n2 * 16 + g * 4) = shi;
        asm volatile("" ::: "memory");
    }
}

// agg_p[i] = sum_{edges dst=i} p_plane[src]   (unweighted, p pre-scaled)
// Group csr slice [offs[4g], offs[4g+4]) is CONTIGUOUS (csr dst-sorted):
// preload it with 2-3 coalesced loads; gathers then have NO dependent csr
// load (addresses via __shfl from registers) -> MLP limited by vmcnt only.
// fp16 accumulate (v_pk_add_f16) halves the VALU work.
__global__ __launch_bounds__(256) void k_gather(const __half2* __restrict__ plane,
        const int* __restrict__ offs, const int* __restrict__ csrs,
        __half2* __restrict__ agg) {
    int lane = threadIdx.x & 63, wave = threadIdx.x >> 6;
    int gwave = blockIdx.x * 4 + wave, nwaves = gridDim.x * 4;
    int q = lane >> 4, s = (lane >> 2) & 3, fq = lane & 3;
    const char* pbase = (const char*)plane;
    for (int g = gwave; g < NGROUP; g += nwaves) {
        int node = g * 4 + q;
        int b = offs[node], e = offs[node + 1];
        int base = __shfl(b, 0);            // offs[4g]
        int tot = __shfl(e, 63) - base;     // group edge count (avg 64, max ~100)
        int cs0 = csrs[base + lane];
        int cs1 = (tot > 64) ? csrs[base + 64 + lane] : 0;
        int cs2 = (tot > 128) ? csrs[base + 128 + lane] : 0;
        int rb = b - base + s;              // this lane's first slot (relative)
        int re = e - base;
        __half2 a0 = __floats2half2_rn(0.f, 0.f), a1 = a0, a2 = a0, a3 = a0;
#define GCH(IDX) {                                                             \
        int idx = (IDX);                                                       \
        bool v = idx < re;                                                     \
        int s0 = __shfl(cs0, idx);                                             \
        int s1 = __shfl(cs1, idx - 64);                                        \
        int s2v = __shfl(cs2, idx - 128);                                      \
        int src = (idx < 64) ? s0 : ((idx < 128) ? s1 : s2v);                  \
        src = v ? src : NN;                                                    \
        int4 gld = *(const int4*)(pbase + ((size_t)src << 6) + (fq << 4));     \
        a0 = __hadd2(a0, ((const __half2*)&gld)[0]);                           \
        a1 = __hadd2(a1, ((const __half2*)&gld)[1]);                           \
        a2 = __hadd2(a2, ((const __half2*)&gld)[2]);                           \
        a3 = __hadd2(a3, ((const __half2*)&gld)[3]); }
        GCH(rb) GCH(rb + 4) GCH(rb + 8) GCH(rb + 12)
        int idx0 = rb + 16;
        while (__any(idx0 < re)) {
            GCH(idx0) GCH(idx0 + 4)
            idx0 += 8;
        }
#undef GCH
        // reduce over eslot s (lanes l, l^4, l^8) in fp16
#pragma unroll
        for (int off = 4; off <= 8; off <<= 1) {
            a0 = __hadd2(a0, __shfl_xor(a0, off));
            a1 = __hadd2(a1, __shfl_xor(a1, off));
            a2 = __hadd2(a2, __shfl_xor(a2, off));
            a3 = __hadd2(a3, __shfl_xor(a3, off));
        }
        if (s == 0) {
            unsigned u0 = *(unsigned*)&a0, u1 = *(unsigned*)&a1;
            unsigned u2 = *(unsigned*)&a2, u3 = *(unsigned*)&a3;
            unsigned long long lo = ((unsigned long long)u1 << 32) | u0;
            unsigned long long hi = ((unsigned long long)u3 << 32) | u2;
            char* dst = (char*)agg + ((size_t)node << 6) + (fq << 4);
            __builtin_nontemporal_store(lo, (unsigned long long*)dst);
            __builtin_nontemporal_store(hi, (unsigned long long*)(dst + 8));
        }
    }
}

// p_out = dinv * relu( (0.9*dinv*(agg+p) + 0.1*h0) @ M_l ), MFMA K=64
__global__ __launch_bounds__(256) void k_matvec(const __half2* __restrict__ ag0,
        const __half2* __restrict__ ag1,
        const __half2* __restrict__ pp0, const __half2* __restrict__ pp1,
        const __half2* __restrict__ h00, const __half2* __restrict__ h01,
        const float* __restrict__ dinv, const __half* __restrict__ frag,
        __half2* __restrict__ po0, __half2* __restrict__ po1) {
    __shared__ __half lds[4][16 * 80];
    int lane = threadIdx.x & 63, wave = threadIdx.x >> 6;
    int gwave = blockIdx.x * 4 + wave, nwaves = gridDim.x * 4;
    int m = lane & 15, g = lane >> 4;
    f16x8 bf[2][4];
    const int4* fb = (const int4*)frag;
#pragma unroll
    for (int kt = 0; kt < 2; kt++)
#pragma unroll
        for (int nb = 0; nb < 4; nb++) {
            int4 r = fb[(kt * 4 + nb) * 64 + lane];
            bf[kt][nb] = *(f16x8*)&r;
        }
    __half* L = &lds[wave][0];
    for (int t = gwave; t < NTILE; t += nwaves) {
        int tb = t * 16;
        float di = dinv[tb + m];
        float c9 = 0.9f * di;
        f32x4 acc[4] = {};
#pragma unroll
        for (int kt = 0; kt < 2; kt++) {
            const __half2* A = kt ? ag1 : ag0;
            const __half2* P = kt ? pp1 : pp0;
            const __half2* H = kt ? h01 : h00;
            size_t base = (size_t)(tb + m) * 16 + g * 4;
            int4 ra = *(const int4*)(A + base);
            int4 rp = *(const int4*)(P + base);
            int4 rh = *(const int4*)(H + base);
            f16x8 af;
#pragma unroll
            for (int u = 0; u < 4; u++) {
                float2 fa = __half22float2(((const __half2*)&ra)[u]);
                float2 fp = __half22float2(((const __half2*)&rp)[u]);
                float2 fh = __half22float2(((const __half2*)&rh)[u]);
                af[2 * u]     = (_Float16)(c9 * (fa.x + fp.x) + 0.1f * fh.x);
                af[2 * u + 1] = (_Float16)(c9 * (fa.y + fp.y) + 0.1f * fh.y);
            }
#pragma unroll
            for (int nb = 0; nb < 4; nb++)
                acc[nb] = __builtin_amdgcn_mfma_f32_16x16x32_f16(af, bf[kt][nb], acc[nb], 0, 0, 0);
        }
        float dvr[4];
#pragma unroll
        for (int r = 0; r < 4; r++) dvr[r] = dinv[tb + g * 4 + r];
#pragma unroll
        for (int nb = 0; nb < 4; nb++)
#pragma unroll
            for (int r = 0; r < 4; r++) {
                int mm = g * 4 + r;
                float y = fmaxf(acc[nb][r], 0.f) * dvr[r];
                L[mm * 80 + nb * 16 + m] = __float2half(y);
            }
        asm volatile("" ::: "memory");
        int n2 = tb + m;
        int4 lo = *(const int4*)&L[m * 80 + g * 8];
        int4 hi = *(const int4*)&L[m * 80 + 32 + g * 8];
        *(int4*)(po0 + (size_t)n2 * 16 + g * 4) = lo;
        *(int4*)(po1 + (size_t)n2 * 16 + g * 4) = hi;
        asm volatile("" ::: "memory");
    }
}

// out = (p*rdinv) @ Wout + bout   (fp32 out)
__global__ __launch_bounds__(256) void k_out(const __half2* __restrict__ pp0,
        const __half2* __restrict__ pp1,
        const float* __restrict__ rdinv, const __half* __restrict__ frag,
        const float* __restrict__ bout, float* __restrict__ out) {
    __shared__ float lds[4][16 * 72];
    int lane = threadIdx.x & 63, wave = threadIdx.x >> 6;
    int gwave = blockIdx.x * 4 + wave, nwaves = gridDim.x * 4;
    int m = lane & 15, g = lane >> 4;
    f16x8 bf[2][4];
    const int4* fb = (const int4*)(frag + 80 * 512);
#pragma unroll
    for (int kt = 0; kt < 2; kt++)
#pragma unroll
        for (int nb = 0; nb < 4; nb++) {
            int4 r = fb[(kt * 4 + nb) * 64 + lane];
            bf[kt][nb] = *(f16x8*)&r;
        }
    float bb[4];
#pragma unroll
    for (int nb = 0; nb < 4; nb++) bb[nb] = bout[nb * 16 + m];
    float* L = &lds[wave][0];
    for (int t = gwave; t < NTILE; t += nwaves) {
        int tb = t * 16;
        float rv = rdinv[tb + m];
        f32x4 acc[4] = {};
#pragma unroll
        for (int kt = 0; kt < 2; kt++) {
            const __half2* P = kt ? pp1 : pp0;
            int4 rp = *(const int4*)(P + (size_t)(tb + m) * 16 + g * 4);
            f16x8 af;
#pragma unroll
            for (int u = 0; u < 4; u++) {
                float2 fp = __half22float2(((const __half2*)&rp)[u]);
                af[2 * u]     = (_Float16)(fp.x * rv);
                af[2 * u + 1] = (_Float16)(fp.y * rv);
            }
#pragma unroll
            for (int nb = 0; nb < 4; nb++)
                acc[nb] = __builtin_amdgcn_mfma_f32_16x16x32_f16(af, bf[kt][nb], acc[nb], 0, 0, 0);
        }
#pragma unroll
        for (int nb = 0; nb < 4; nb++)
#pragma unroll
            for (int r = 0; r < 4; r++)
                L[(g * 4 + r) * 72 + nb * 16 + m] = acc[nb][r] + bb[nb];
        asm volatile("" ::: "memory");
#pragma unroll
        for (int pass = 0; pass < 4; pass++) {
            int nl = pass * 4 + g;
            float4 v = *(const float4*)&L[nl * 72 + m * 4];
            *(float4*)(out + (size_t)(tb + nl) * 64 + m * 4) = v;
        }
        asm volatile("" ::: "memory");
    }
}

// ---------------- launch ----------------

static inline size_t al256(size_t x) { return (x + 255) & ~(size_t)255; }

extern "C" void kernel_launch(void* const* d_in, const int* in_sizes, int n_in,
                              void* d_out, int out_size, void* d_ws, size_t ws_size,
                              hipStream_t stream) {
    const float* x    = (const float*)d_in[0];
    const int*   ei   = (const int*)d_in[1];
    const float* W0   = (const float*)d_in[2];
    const float* b0   = (const float*)d_in[3];
    const float* Ws   = (const float*)d_in[4];
    const float* Wout = (const float*)d_in[5];
    const float* bout = (const float*)d_in[6];
    float* out = (float*)d_out;

    char* w = (char*)d_ws;
    size_t off = 0;
    const size_t PL  = (size_t)(NN + 1) * 16 * sizeof(__half2);  // plane +1 zero row
    const size_t PLS = (size_t)NN * 16 * sizeof(__half2);        // plane, no extra row
    int* gh      = (int*)(w + off); off = al256(off + (size_t)256 * 256 * 4);
    int* bbase   = (int*)(w + off); off = al256(off + (size_t)257 * 4);
    int2* part   = (int2*)(w + off); off = al256(off + (size_t)NE * 8);
    int* csrs    = (int*)(w + off); off = al256(off + ((size_t)NE + 192) * 4);
    int* offs    = (int*)(w + off); off = al256(off + ((size_t)NN + 1) * 4);
    float* dinv  = (float*)(w + off); off = al256(off + (size_t)NN * 4);
    float* rdinv = (float*)(w + off); off = al256(off + (size_t)NN * 4);
    __half* frag = (__half*)(w + off); off = al256(off + (size_t)88 * 512 * 2);
    __half2* pA0 = (__half2*)(w + off); off = al256(off + PL);
    __half2* pA1 = (__half2*)(w + off); off = al256(off + PL);
    __half2* pB0 = (__half2*)(w + off); off = al256(off + PL);
    __half2* pB1 = (__half2*)(w + off); off = al256(off + PL);
    __half2* g00 = (__half2*)(w + off); off = al256(off + PLS);
    __half2* g01 = (__half2*)(w + off); off = al256(off + PLS);
    __half2* ag0 = (__half2*)(w + off); off = al256(off + PLS);
    __half2* ag1 = (__half2*)(w + off); off = al256(off + PLS);

    k_hist<<<256, 256, 0, stream>>>(ei, gh);
    k_scanhist<<<1, 256, 0, stream>>>(gh, bbase);
    k_part<<<256, 256, 0, stream>>>(ei, gh, part);
    k_bsort<<<NBUCKB, 256, 0, stream>>>(part, bbase, csrs, offs, dinv, rdinv);
    k_zrow<<<1, 64, 0, stream>>>(pA0, pA1, pB0, pB1);
    k_makefrag<<<88, 64, 0, stream>>>(W0, Ws, Wout, frag);

    k_layer0<<<784, 256, 0, stream>>>(x, frag, b0, dinv, pA0, pA1, g00, g01);

    const __half2 *c0 = pA0, *c1 = pA1;
    __half2 *n0 = pB0, *n1 = pB1;
    for (int l = 0; l < NLAYERS; l++) {
        k_gather<<<1563, 256, 0, stream>>>(c0, offs, csrs, ag0);
        k_gather<<<1563, 256, 0, stream>>>(c1, offs, csrs, ag1);
        k_matvec<<<784, 256, 0, stream>>>(ag0, ag1, c0, c1, g00, g01,
                                          dinv, frag + (16 + l * 8) * 512, n0, n1);
        const __half2* t0 = n0; const __half2* t1 = n1;
        n0 = (__half2*)c0; n1 = (__half2*)c1;
        c0 = t0; c1 = t1;
    }
    k_out<<<784, 256, 0, stream>>>(c0, c1, rdinv, frag, bout, out);
}

// Round 8
// 227.584 us; speedup vs baseline: 6.0928x; 1.2645x over previous
//
#include <hip/hip_runtime.h>
#include <hip/hip_fp16.h>
#include <math.h>

#define NN 50000
#define NE 800000
#define NLAYERS 8
#define NTILE (NN / 16)                     // 3125 16-node tiles
#define EPB (NE / 256)                      // 3125 edges per hist/part block
#define NBUCKB ((NN + 255) / 256)           // 196 buckets in use
#define BCAP 5120                           // max edges per bucket
#define CSRCAP 512                          // max edges per 16-node tile (mean 256, 16 sigma)

typedef _Float16 f16x8 __attribute__((ext_vector_type(8)));
typedef float f32x4 __attribute__((ext_vector_type(4)));

// ---------------- CSR build: 4-pass radix partition (unchanged) ----------------

__global__ __launch_bounds__(256) void k_hist(const int* __restrict__ ei,
                                              int* __restrict__ gh) {
    __shared__ int h[256];
    h[threadIdx.x] = 0;
    __syncthreads();
    int base = blockIdx.x * EPB;
    for (int i = threadIdx.x; i < EPB; i += 256) {
        int d = __builtin_nontemporal_load(ei + NE + base + i);
        atomicAdd(&h[d >> 8], 1);
    }
    __syncthreads();
    gh[blockIdx.x * 256 + threadIdx.x] = h[threadIdx.x];
}

__global__ void k_scanhist(int* __restrict__ gh, int* __restrict__ bbase) {
    __shared__ int tot[256];
    int t = threadIdx.x;
    int run = 0;
    for (int blk = 0; blk < 256; blk++) {
        int v = gh[blk * 256 + t];
        gh[blk * 256 + t] = run;
        run += v;
    }
    tot[t] = run;
    __syncthreads();
    for (int off = 1; off < 256; off <<= 1) {
        int u = (t >= off) ? tot[t - off] : 0;
        __syncthreads();
        tot[t] += u;
        __syncthreads();
    }
    int ebase = tot[t] - run;
    for (int blk = 0; blk < 256; blk++) gh[blk * 256 + t] += ebase;
    bbase[t] = ebase;
    if (t == 255) bbase[256] = NE;
}

__global__ __launch_bounds__(256) void k_part(const int* __restrict__ ei,
                                              const int* __restrict__ gh,
                                              int2* __restrict__ part) {
    __shared__ int lcnt[256];
    int t = threadIdx.x;
    lcnt[t] = gh[blockIdx.x * 256 + t];
    __syncthreads();
    int base = blockIdx.x * EPB;
    for (int i = t; i < EPB; i += 256) {
        int s = __builtin_nontemporal_load(ei + base + i);
        int d = __builtin_nontemporal_load(ei + NE + base + i);
        int pos = atomicAdd(&lcnt[d >> 8], 1);
        int2 e; e.x = s; e.y = d;
        part[pos] = e;
    }
}

__global__ __launch_bounds__(256) void k_bsort(const int2* __restrict__ part,
                                               const int* __restrict__ bbase,
                                               int* __restrict__ csrs,
                                               int* __restrict__ offs,
                                               float* __restrict__ dinv,
                                               float* __restrict__ rdinv) {
    __shared__ int ssrc[BCAP];
    __shared__ unsigned char sdlo[BCAP];
    __shared__ int dcnt[256], dpos[256], scan[256];
    int b = blockIdx.x, t = threadIdx.x;
    int base0 = bbase[b], base1 = bbase[b + 1];
    int n = base1 - base0;
    if (n > BCAP) n = BCAP;
    dcnt[t] = 0;
    __syncthreads();
    for (int i = t; i < n; i += 256) {
        int2 e = part[base0 + i];
        ssrc[i] = e.x;
        int dlo = e.y & 255;
        sdlo[i] = (unsigned char)dlo;
        atomicAdd(&dcnt[dlo], 1);
    }
    __syncthreads();
    int cnt = dcnt[t];
    scan[t] = cnt;
    __syncthreads();
    for (int off = 1; off < 256; off <<= 1) {
        int u = (t >= off) ? scan[t - off] : 0;
        __syncthreads();
        scan[t] += u;
        __syncthreads();
    }
    int ebase = scan[t] - cnt;
    dpos[t] = ebase;
    __syncthreads();
    for (int i = t; i < n; i += 256) {
        int d = sdlo[i];
        int r = atomicAdd(&dpos[d], 1);
        csrs[base0 + r] = ssrc[i];
    }
    int gdst = b * 256 + t;
    if (gdst < NN) {
        offs[gdst] = base0 + ebase;
        float dd = (float)(cnt + 1);
        dinv[gdst] = rsqrtf(dd);
        rdinv[gdst] = sqrtf(dd);
    } else if (gdst == NN) {
        offs[NN] = NE;
    }
}

// ---------------- other setup ----------------
// MERGED row layout: row[node] = 128B = 64 halves (feats 0-63). One cache line.

// zero row NN of pA and pB (gather target for masked slots)
__global__ void k_zrow(__half2* a, __half2* b) {
    int t = threadIdx.x;
    __half2 z = __floats2half2_rn(0.f, 0.f);
    if (t < 32) a[NN * 32 + t] = z;
    else b[NN * 32 + (t & 31)] = z;
}

// frag[fid][lane][j] = B[k = kt*32 + (lane>>4)*8 + j][n = nb*16 + (lane&15)]
// fid 0..15: W0; 16..79: M_l = (1-b)I + b*Ws[l]; 80..87: Wout.
__global__ void k_makefrag(const float* __restrict__ W0, const float* __restrict__ Ws,
                           const float* __restrict__ Wout, __half* __restrict__ frag) {
    int fid = blockIdx.x;
    int lane = threadIdx.x;
    int m = lane & 15, g = lane >> 4;
#pragma unroll
    for (int j = 0; j < 8; j++) {
        float v;
        if (fid < 16) {
            int kt = fid >> 2, nb = fid & 3;
            int k = kt * 32 + g * 8 + j, n = nb * 16 + m;
            v = W0[k * 64 + n];
        } else if (fid < 80) {
            int t = fid - 16;
            int l = t >> 3, kt = (t >> 2) & 1, nb = t & 3;
            float beta = logf(0.5f / (float)(l + 1) + 1.0f);
            int k = kt * 32 + g * 8 + j, n = nb * 16 + m;
            v = beta * Ws[l * 4096 + k * 64 + n] + ((k == n) ? (1.0f - beta) : 0.0f);
        } else {
            int t = fid - 80;
            int kt = t >> 2, nb = t & 3;
            int k = kt * 32 + g * 8 + j, n = nb * 16 + m;
            v = Wout[k * 64 + n];
        }
        frag[fid * 512 + lane * 8 + j] = __float2half(v);
    }
}

// ---------------- compute kernels ----------------

// h = relu(x @ W0 + b0): MFMA, writes merged p rows (dinv-scaled) + h0 rows
__global__ __launch_bounds__(256) void k_layer0(const float* __restrict__ x,
        const __half* __restrict__ frag, const float* __restrict__ b0,
        const float* __restrict__ dinv,
        char* __restrict__ pbuf, char* __restrict__ h0buf) {
    __shared__ __half lds[4][16 * 80];
    int lane = threadIdx.x & 63, wave = threadIdx.x >> 6;
    int gwave = blockIdx.x * 4 + wave, nwaves = gridDim.x * 4;
    int m = lane & 15, g = lane >> 4;
    f16x8 bf[4][4];
    const int4* fb = (const int4*)frag;
#pragma unroll
    for (int kt = 0; kt < 4; kt++)
#pragma unroll
        for (int nb = 0; nb < 4; nb++) {
            int4 r = fb[(kt * 4 + nb) * 64 + lane];
            bf[kt][nb] = *(f16x8*)&r;
        }
    float bb[4];
#pragma unroll
    for (int nb = 0; nb < 4; nb++) bb[nb] = b0[nb * 16 + m];
    __half* L = &lds[wave][0];
    for (int t = gwave; t < NTILE; t += nwaves) {
        int tb = t * 16;
        f32x4 acc[4] = {};
        const float* xrow = x + (size_t)(tb + m) * 128;
#pragma unroll
        for (int kt = 0; kt < 4; kt++) {
            float4 r0 = *(const float4*)(xrow + kt * 32 + g * 8);
            float4 r1 = *(const float4*)(xrow + kt * 32 + g * 8 + 4);
            f16x8 af;
            af[0] = (_Float16)r0.x; af[1] = (_Float16)r0.y;
            af[2] = (_Float16)r0.z; af[3] = (_Float16)r0.w;
            af[4] = (_Float16)r1.x; af[5] = (_Float16)r1.y;
            af[6] = (_Float16)r1.z; af[7] = (_Float16)r1.w;
#pragma unroll
            for (int nb = 0; nb < 4; nb++)
                acc[nb] = __builtin_amdgcn_mfma_f32_16x16x32_f16(af, bf[kt][nb], acc[nb], 0, 0, 0);
        }
#pragma unroll
        for (int nb = 0; nb < 4; nb++)
#pragma unroll
            for (int r = 0; r < 4; r++) {
                int mm = g * 4 + r;
                float y = fmaxf(acc[nb][r] + bb[nb], 0.f);
                L[mm * 80 + nb * 16 + m] = __float2half(y);
            }
        asm volatile("" ::: "memory");
        int n2 = tb + m;
        float dv = dinv[n2];
        int4 lo = *(const int4*)&L[m * 80 + g * 8];        // feats g*8..+7
        int4 hi = *(const int4*)&L[m * 80 + 32 + g * 8];   // feats 32+g*8..+7
        *(int4*)(h0buf + (size_t)n2 * 128 + g * 16) = lo;
        *(int4*)(h0buf + (size_t)n2 * 128 + 64 + g * 16) = hi;
        int4 slo, shi;
        const __half2* l2 = (const __half2*)&lo; __half2* s2 = (__half2*)&slo;
        const __half2* h2 = (const __half2*)&hi; __half2* t2 = (__half2*)&shi;
#pragma unroll
        for (int u = 0; u < 4; u++) {
            float2 a = __half22float2(l2[u]); s2[u] = __floats2half2_rn(a.x * dv, a.y * dv);
            float2 b = __half22float2(h2[u]); t2[u] = __floats2half2_rn(b.x * dv, b.y * dv);
        }
        *(int4*)(pbuf + (size_t)n2 * 128 + g * 16) = slo;
        *(int4*)(pbuf + (size_t)n2 * 128 + 64 + g * 16) = shi;
        asm volatile("" ::: "memory");
    }
}

// FUSED layer: per 16-node tile (one wave): stage csr slice in LDS ->
// gather both planes (lane = node q(4) x slot s(2) x fq(8), 16B each,
// full 128B row = 1 cache line per edge) -> park agg in LDS (144B stride)
// -> blend + MFMA K=64 -> transpose -> write p_out (dinv-scaled).
// No __syncthreads anywhere: all LDS regions are wave-private.
__global__ __launch_bounds__(256) void k_flayer(
        const char* __restrict__ pbuf, const char* __restrict__ h0buf,
        const float* __restrict__ dinv, const __half* __restrict__ frag,
        const int* __restrict__ offs, const int* __restrict__ csrs,
        char* __restrict__ pout) {
    __shared__ int    csrl[4][CSRCAP];     // 2048B/wave
    __shared__ __half aggl[4][16 * 72];    // 144B row stride, 2304B/wave
    __shared__ __half outl[4][16 * 80];    // 2560B/wave
    int lane = threadIdx.x & 63, wave = threadIdx.x >> 6;
    int t = blockIdx.x * 4 + wave;
    if (t >= NTILE) return;
    int tb = t * 16;
    int m = lane & 15, g = lane >> 4;

    // B fragments for this layer
    f16x8 bf[2][4];
    const int4* fb = (const int4*)frag;
#pragma unroll
    for (int kt = 0; kt < 2; kt++)
#pragma unroll
        for (int nb = 0; nb < 4; nb++) {
            int4 r = fb[(kt * 4 + nb) * 64 + lane];
            bf[kt][nb] = *(f16x8*)&r;
        }

    // tile edge range + csr slice -> LDS (coalesced; slice is contiguous)
    int offv = 0;
    if (lane < 17) offv = offs[tb + lane];
    int base = __shfl(offv, 0);
    int tot  = __shfl(offv, 16) - base;
    if (tot > CSRCAP) tot = CSRCAP;
    int* cl = csrl[wave];
    for (int i = lane; i < tot; i += 64)
        cl[i] = __builtin_nontemporal_load(csrs + base + i);

    // gather: 4 passes x 4 nodes, s = 2 edge slots, fq = 8 x 16B (128B row)
    int q = lane >> 4, s = (lane >> 3) & 1, fq = lane & 7;
    char* al = (char*)&aggl[wave][0];
#pragma unroll 1
    for (int p = 0; p < 4; p++) {
        int r0 = __shfl(offv, 4 * p + q) - base + s;   // first slot for this lane
        int r1 = __shfl(offv, 4 * p + q + 1) - base;   // end (exclusive)
        __half2 a0 = __floats2half2_rn(0.f, 0.f), a1 = a0, a2 = a0, a3 = a0;
#define GCH(IT) {                                                              \
        int idx = r0 + 2 * (IT);                                               \
        bool v = idx < r1;                                                     \
        int src = cl[v ? idx : 0];                                             \
        src = v ? src : NN;                                                    \
        int4 gld = *(const int4*)(pbuf + (size_t)src * 128 + fq * 16);         \
        a0 = __hadd2(a0, ((const __half2*)&gld)[0]);                           \
        a1 = __hadd2(a1, ((const __half2*)&gld)[1]);                           \
        a2 = __hadd2(a2, ((const __half2*)&gld)[2]);                           \
        a3 = __hadd2(a3, ((const __half2*)&gld)[3]); }
        GCH(0) GCH(1) GCH(2) GCH(3)
        int it = 4;
        while (__any(r0 + 2 * it < r1)) {
            GCH(it) GCH(it + 1)
            it += 2;
        }
#undef GCH
        // reduce over slot s (xor 8), park in s==0 lanes
        a0 = __hadd2(a0, __shfl_xor(a0, 8));
        a1 = __hadd2(a1, __shfl_xor(a1, 8));
        a2 = __hadd2(a2, __shfl_xor(a2, 8));
        a3 = __hadd2(a3, __shfl_xor(a3, 8));
        if (s == 0) {
            int4 v;
            v.x = *(int*)&a0; v.y = *(int*)&a1; v.z = *(int*)&a2; v.w = *(int*)&a3;
            *(int4*)(al + (4 * p + q) * 144 + fq * 16) = v;
        }
    }
    asm volatile("" ::: "memory");

    // blend + MFMA (node = m, feat-k chunk = kt*32 + g*8)
    float di = dinv[tb + m];
    float c9 = 0.9f * di;
    f32x4 acc[4] = {};
#pragma unroll
    for (int kt = 0; kt < 2; kt++) {
        int4 ra = *(const int4*)(al + m * 144 + kt * 64 + g * 16);
        int4 rp = *(const int4*)(pbuf + (size_t)(tb + m) * 128 + kt * 64 + g * 16);
        int4 rh = *(const int4*)(h0buf + (size_t)(tb + m) * 128 + kt * 64 + g * 16);
        f16x8 af;
#pragma unroll
        for (int u = 0; u < 4; u++) {
            float2 fa = __half22float2(((const __half2*)&ra)[u]);
            float2 fp = __half22float2(((const __half2*)&rp)[u]);
            float2 fh = __half22float2(((const __half2*)&rh)[u]);
            af[2 * u]     = (_Float16)(c9 * (fa.x + fp.x) + 0.1f * fh.x);
            af[2 * u + 1] = (_Float16)(c9 * (fa.y + fp.y) + 0.1f * fh.y);
        }
#pragma unroll
        for (int nb = 0; nb < 4; nb++)
            acc[nb] = __builtin_amdgcn_mfma_f32_16x16x32_f16(af, bf[kt][nb], acc[nb], 0, 0, 0);
    }

    // epilogue: relu * dinv, transpose via LDS, merged-row write
    __half* L = &outl[wave][0];
    float dvr[4];
#pragma unroll
    for (int r = 0; r < 4; r++) dvr[r] = dinv[tb + g * 4 + r];
#pragma unroll
    for (int nb = 0; nb < 4; nb++)
#pragma unroll
        for (int r = 0; r < 4; r++) {
            int mm = g * 4 + r;
            float y = fmaxf(acc[nb][r], 0.f) * dvr[r];
            L[mm * 80 + nb * 16 + m] = __float2half(y);
        }
    asm volatile("" ::: "memory");
    int n2 = tb + m;
    int4 lo = *(const int4*)&L[m * 80 + g * 8];
    int4 hi = *(const int4*)&L[m * 80 + 32 + g * 8];
    *(int4*)(pout + (size_t)n2 * 128 + g * 16) = lo;
    *(int4*)(pout + (size_t)n2 * 128 + 64 + g * 16) = hi;
}

// out = (p*rdinv) @ Wout + bout   (fp32 out)
__global__ __launch_bounds__(256) void k_out(const char* __restrict__ pbuf,
        const float* __restrict__ rdinv, const __half* __restrict__ frag,
        const float* __restrict__ bout, float* __restrict__ out) {
    __shared__ float lds[4][16 * 72];
    int lane = threadIdx.x & 63, wave = threadIdx.x >> 6;
    int gwave = blockIdx.x * 4 + wave, nwaves = gridDim.x * 4;
    int m = lane & 15, g = lane >> 4;
    f16x8 bf[2][4];
    const int4* fb = (const int4*)(frag + 80 * 512);
#pragma unroll
    for (int kt = 0; kt < 2; kt++)
#pragma unroll
        for (int nb = 0; nb < 4; nb++) {
            int4 r = fb[(kt * 4 + nb) * 64 + lane];
            bf[kt][nb] = *(f16x8*)&r;
        }
    float bb[4];
#pragma unroll
    for (int nb = 0; nb < 4; nb++) bb[nb] = bout[nb * 16 + m];
    float* L = &lds[wave][0];
    for (int t = gwave; t < NTILE; t += nwaves) {
        int tb = t * 16;
        float rv = rdinv[tb + m];
        f32x4 acc[4] = {};
#pragma unroll
        for (int kt = 0; kt < 2; kt++) {
            int4 rp = *(const int4*)(pbuf + (size_t)(tb + m) * 128 + kt * 64 + g * 16);
            f16x8 af;
#pragma unroll
            for (int u = 0; u < 4; u++) {
                float2 fp = __half22float2(((const __half2*)&rp)[u]);
                af[2 * u]     = (_Float16)(fp.x * rv);
                af[2 * u + 1] = (_Float16)(fp.y * rv);
            }
#pragma unroll
            for (int nb = 0; nb < 4; nb++)
                acc[nb] = __builtin_amdgcn_mfma_f32_16x16x32_f16(af, bf[kt][nb], acc[nb], 0, 0, 0);
        }
#pragma unroll
        for (int nb = 0; nb < 4; nb++)
#pragma unroll
            for (int r = 0; r < 4; r++)
                L[(g * 4 + r) * 72 + nb * 16 + m] = acc[nb][r] + bb[nb];
        asm volatile("" ::: "memory");
#pragma unroll
        for (int pass = 0; pass < 4; pass++) {
            int nl = pass * 4 + g;
            float4 v = *(const float4*)&L[nl * 72 + m * 4];
            *(float4*)(out + (size_t)(tb + nl) * 64 + m * 4) = v;
        }
        asm volatile("" ::: "memory");
    }
}

// ---------------- launch ----------------

static inline size_t al256(size_t x) { return (x + 255) & ~(size_t)255; }

extern "C" void kernel_launch(void* const* d_in, const int* in_sizes, int n_in,
                              void* d_out, int out_size, void* d_ws, size_t ws_size,
                              hipStream_t stream) {
    const float* x    = (const float*)d_in[0];
    const int*   ei   = (const int*)d_in[1];
    const float* W0   = (const float*)d_in[2];
    const float* b0   = (const float*)d_in[3];
    const float* Ws   = (const float*)d_in[4];
    const float* Wout = (const float*)d_in[5];
    const float* bout = (const float*)d_in[6];
    float* out = (float*)d_out;

    char* w = (char*)d_ws;
    size_t off = 0;
    const size_t ROWS = (size_t)(NN + 1) * 128;   // merged plane, +1 zero row
    int* gh      = (int*)(w + off); off = al256(off + (size_t)256 * 256 * 4);
    int* bbase   = (int*)(w + off); off = al256(off + (size_t)257 * 4);
    int2* part   = (int2*)(w + off); off = al256(off + (size_t)NE * 8);
    int* csrs    = (int*)(w + off); off = al256(off + ((size_t)NE + 256) * 4);
    int* offs    = (int*)(w + off); off = al256(off + ((size_t)NN + 1) * 4);
    float* dinv  = (float*)(w + off); off = al256(off + (size_t)NN * 4);
    float* rdinv = (float*)(w + off); off = al256(off + (size_t)NN * 4);
    __half* frag = (__half*)(w + off); off = al256(off + (size_t)88 * 512 * 2);
    char* pA     = (char*)(w + off); off = al256(off + ROWS);
    char* pB     = (char*)(w + off); off = al256(off + ROWS);
    char* h0b    = (char*)(w + off); off = al256(off + (size_t)NN * 128);

    k_hist<<<256, 256, 0, stream>>>(ei, gh);
    k_scanhist<<<1, 256, 0, stream>>>(gh, bbase);
    k_part<<<256, 256, 0, stream>>>(ei, gh, part);
    k_bsort<<<NBUCKB, 256, 0, stream>>>(part, bbase, csrs, offs, dinv, rdinv);
    k_zrow<<<1, 64, 0, stream>>>((__half2*)pA, (__half2*)pB);
    k_makefrag<<<88, 64, 0, stream>>>(W0, Ws, Wout, frag);

    k_layer0<<<784, 256, 0, stream>>>(x, frag, b0, dinv, pA, h0b);

    const char* cur = pA;
    char* nxt = pB;
    for (int l = 0; l < NLAYERS; l++) {
        k_flayer<<<(NTILE + 3) / 4, 256, 0, stream>>>(cur, h0b, dinv,
                frag + (16 + l * 8) * 512, offs, csrs, nxt);
        char* t2 = nxt;
        nxt = (char*)cur;
        cur = t2;
    }
    k_out<<<784, 256, 0, stream>>>(cur, rdinv, frag, bout, out);
}